// Round 2
// baseline (5183.892 us; speedup 1.0000x reference)
//
#include <hip/hip_runtime.h>

typedef float f32x4_t __attribute__((ext_vector_type(4)));
typedef short bf16x8_t __attribute__((ext_vector_type(8)));

#define MFMA16(A,B,C) __builtin_amdgcn_mfma_f32_16x16x32_bf16((A),(B),(C),0,0,0)

static constexpr int CC = 256;      // channels
static constexpr int NP = 3600;     // valid tokens
static constexpr int PP = 3648;     // padded tokens (57*64)
static constexpr int CPOS = 3906;   // canvas positions (62*63, incl. slack)

static constexpr size_t SZ_F  = (size_t)PP*CC*4;
static constexpr size_t SZ_H  = (size_t)PP*CC*2;
static constexpr size_t SZ_CV = (size_t)CPOS*512*2;

static constexpr size_t O_SF   = 0;
static constexpr size_t O_STH  = O_SF   + 3*SZ_F;
static constexpr size_t O_STL  = O_STH  + 3*SZ_H;
static constexpr size_t O_SCH  = O_STL  + 3*SZ_H;
static constexpr size_t O_SCL  = O_SCH  + 3*SZ_H;
static constexpr size_t O_CORH = O_SCL  + 3*SZ_H;
static constexpr size_t O_CORL = O_CORH + 3*SZ_H;
static constexpr size_t O_CVH  = O_CORL + 3*SZ_H;
static constexpr size_t O_CVL  = O_CVH  + 3*SZ_CV;
static constexpr size_t O_WLH  = O_CVL  + 3*SZ_CV;
static constexpr size_t O_WLL  = O_WLH  + 131072;
static constexpr size_t O_WURH = O_WLL  + 131072;
static constexpr size_t O_WURL = O_WURH + 524288;
static constexpr size_t O_WOH  = O_WURL + 524288;
static constexpr size_t O_WOL  = O_WOH  + 262144;
static constexpr size_t O_WKH  = O_WOL  + 262144;
static constexpr size_t O_WKL  = O_WKH  + 2359296;
// X region: flash partials (flash->merge) OVERLAID with AH/AL/U/PRH/PRL (conv->gruo)
static constexpr size_t O_X    = O_WKL  + 2359296;
static constexpr size_t O_PML  = O_X;                 // 342*nspl*512 B
static constexpr size_t O_PO   = O_X + 1048576;       // 342*nspl*65536 B
static constexpr size_t O_AH   = O_X;
static constexpr size_t O_AL   = O_AH + 3*SZ_H;
static constexpr size_t O_U    = O_AL + 3*SZ_H;
static constexpr size_t O_PRH  = O_U  + 3*SZ_F;
static constexpr size_t O_PRL  = O_PRH + 3*SZ_H;

#define WSPTR(T, OFF) ((T*)(ws + (OFF)))

__device__ __forceinline__ unsigned short f2bf(float f){
  unsigned u = __builtin_bit_cast(unsigned, f);
  u += 0x7FFFu + ((u >> 16) & 1u);
  return (unsigned short)(u >> 16);
}
__device__ __forceinline__ float bf2f(unsigned short h){
  unsigned u = ((unsigned)h) << 16;
  return __builtin_bit_cast(float, u);
}
__device__ __forceinline__ void split_bf(float x, unsigned short &h, unsigned short &l){
  h = f2bf(x);
  l = f2bf(x - bf2f(h));
}

// ---- shared GEMM pieces for corr/conv/gru: 64x64 tile, LDS stride 72 ------
__device__ __forceinline__ void stage64(unsigned short* dst, const unsigned short* __restrict__ src, int ld){
  int t = threadIdx.x, r = t >> 2, c8 = (t & 3) * 8;
  *(bf16x8_t*)&dst[r*72 + c8]      = *(const bf16x8_t*)&src[(size_t)r*ld + c8];
  *(bf16x8_t*)&dst[r*72 + c8 + 32] = *(const bf16x8_t*)&src[(size_t)r*ld + c8 + 32];
}

__device__ __forceinline__ void mfma64(const unsigned short* Ah, const unsigned short* Al,
                                       const unsigned short* Bh, const unsigned short* Bl,
                                       f32x4_t acc[4], int lane, int wid){
  int kb = (lane >> 4) * 8, lr = lane & 15;
  int arow = wid*16 + lr;
  #pragma unroll
  for(int kk = 0; kk < 2; kk++){
    bf16x8_t ah = *(const bf16x8_t*)&Ah[arow*72 + kk*32 + kb];
    bf16x8_t al = *(const bf16x8_t*)&Al[arow*72 + kk*32 + kb];
    #pragma unroll
    for(int ct = 0; ct < 4; ct++){
      int brow = ct*16 + lr;
      bf16x8_t bh = *(const bf16x8_t*)&Bh[brow*72 + kk*32 + kb];
      bf16x8_t bl = *(const bf16x8_t*)&Bl[brow*72 + kk*32 + kb];
      acc[ct] = MFMA16(ah, bh, acc[ct]);
      acc[ct] = MFMA16(ah, bl, acc[ct]);
      acc[ct] = MFMA16(al, bh, acc[ct]);
    }
  }
}

// ---- zero canvases --------------------------------------------------------
__global__ void k_zero(char* ws){
  size_t n = (6*SZ_CV)/16;
  uint4* p = (uint4*)(ws + O_CVH);
  uint4 z = {0,0,0,0};
  for(size_t x = (size_t)blockIdx.x*256 + threadIdx.x; x < n; x += (size_t)gridDim.x*256) p[x] = z;
}

// ---- split weights --------------------------------------------------------
__global__ void k_weights(char* ws, const float* __restrict__ Wlin, const float* __restrict__ Wup,
                          const float* __restrict__ Wrs, const float* __restrict__ Wo,
                          const float* __restrict__ Wcf){
  const size_t N1 = 65536, N2 = N1 + 262144, N3 = N2 + 131072, N4 = N3 + 1179648;
  for(size_t x = (size_t)blockIdx.x*256 + threadIdx.x; x < N4; x += (size_t)gridDim.x*256){
    float v; unsigned short *dh, *dl; size_t off;
    if(x < N1){
      v = Wlin[x]; dh = WSPTR(unsigned short, O_WLH); dl = WSPTR(unsigned short, O_WLL); off = x;
    } else if(x < N2){
      size_t i = x - N1; int e = (int)(i >> 9), c = (int)(i & 511);
      v = (e < 256) ? Wup[(size_t)e*512 + c] : Wrs[(size_t)(e-256)*512 + c];
      dh = WSPTR(unsigned short, O_WURH); dl = WSPTR(unsigned short, O_WURL); off = i;
    } else if(x < N3){
      size_t i = x - N2; v = Wo[i];
      dh = WSPTR(unsigned short, O_WOH); dl = WSPTR(unsigned short, O_WOL); off = i;
    } else {
      size_t i = x - N3; int t = (int)(i % 9); size_t rest = i / 9;
      int ic = (int)(rest & 511), o = (int)(rest >> 9);
      v = Wcf[i]; off = (size_t)t*131072 + (size_t)o*512 + ic;
      dh = WSPTR(unsigned short, O_WKH); dl = WSPTR(unsigned short, O_WKL);
    }
    unsigned short h, l; split_bf(v, h, l);
    dh[off] = h; dl[off] = l;
  }
}

// ---- transpose inputs to token-major + make bf16 copies -------------------
__global__ __launch_bounds__(256) void k_transpose(char* ws, const float* __restrict__ in0,
                                                   const float* __restrict__ in1, const float* __restrict__ in2){
  __shared__ float tile[64*65];
  int z = blockIdx.z;
  const float* in = z == 0 ? in0 : (z == 1 ? in1 : in2);
  int p0 = blockIdx.x*64, c0 = blockIdx.y*64;
  float* sF = WSPTR(float, O_SF) + (size_t)z*PP*CC;
  unsigned short* sTh = WSPTR(unsigned short, O_STH) + (size_t)z*PP*CC;
  unsigned short* sTl = WSPTR(unsigned short, O_STL) + (size_t)z*PP*CC;
  unsigned short* sCh = WSPTR(unsigned short, O_SCH) + (size_t)z*PP*CC;
  unsigned short* sCl = WSPTR(unsigned short, O_SCL) + (size_t)z*PP*CC;
  int t = threadIdx.x, pl = t & 63, cq = t >> 6;
  #pragma unroll
  for(int rr = 0; rr < 16; rr++){
    int cl = rr*4 + cq, p = p0 + pl, c = c0 + cl;
    float v = (p < NP) ? in[(size_t)c*NP + p] : 0.f;
    tile[cl*65 + pl] = v;
    if(p < NP){
      unsigned short h, l; split_bf(v, h, l);
      sCh[(size_t)c*PP + p] = h; sCl[(size_t)c*PP + p] = l;
    }
  }
  __syncthreads();
  #pragma unroll
  for(int rr = 0; rr < 16; rr++){
    int prow = rr*4 + cq, p = p0 + prow, cl = pl;
    if(p < NP){
      float v = tile[cl*65 + prow];
      int c = c0 + cl;
      sF[(size_t)p*CC + c] = v;
      unsigned short h, l; split_bf(v, h, l);
      sTh[(size_t)p*CC + c] = h; sTl[(size_t)p*CC + c] = l;
    }
  }
}

// ---- corr = stateT @ W_lin^T ----------------------------------------------
__global__ __launch_bounds__(256,4) void k_corr(char* ws){
  __shared__ unsigned short Ah[64*72], Al[64*72], Bh[64*72], Bl[64*72];
  int z = blockIdx.z, m0 = blockIdx.x*64, n0 = blockIdx.y*64;
  const unsigned short* aH = WSPTR(const unsigned short, O_STH) + (size_t)z*PP*CC;
  const unsigned short* aL = WSPTR(const unsigned short, O_STL) + (size_t)z*PP*CC;
  const unsigned short* bH = WSPTR(const unsigned short, O_WLH);
  const unsigned short* bL = WSPTR(const unsigned short, O_WLL);
  unsigned short* cH = WSPTR(unsigned short, O_CORH) + (size_t)z*PP*CC;
  unsigned short* cL = WSPTR(unsigned short, O_CORL) + (size_t)z*PP*CC;
  int lane = threadIdx.x & 63, wid = threadIdx.x >> 6;
  f32x4_t acc[4] = {};
  for(int k0 = 0; k0 < 256; k0 += 64){
    __syncthreads();
    stage64(Ah, aH + (size_t)m0*256 + k0, 256);
    stage64(Al, aL + (size_t)m0*256 + k0, 256);
    stage64(Bh, bH + (size_t)n0*256 + k0, 256);
    stage64(Bl, bL + (size_t)n0*256 + k0, 256);
    __syncthreads();
    mfma64(Ah, Al, Bh, Bl, acc, lane, wid);
  }
  #pragma unroll
  for(int r = 0; r < 4; r++){
    int i = m0 + wid*16 + (lane >> 4)*4 + r;
    if(i >= NP) continue;
    #pragma unroll
    for(int ct = 0; ct < 4; ct++){
      int c = n0 + ct*16 + (lane & 15);
      unsigned short h, l; split_bf(acc[ct][r], h, l);
      cH[(size_t)i*CC + c] = h; cL[(size_t)i*CC + c] = l;
    }
  }
}

// ---- split-K flash attention (S^T orientation), partials to ws ------------
__global__ __launch_bounds__(256,2) void k_flash(char* ws, int nspl){
  __shared__ unsigned short KV[32768];            // 64KB: K [64][256] h|l  /  V [256][64] h|l
  __shared__ unsigned short PBh[4][1024], PBl[4][1024]; // per-wave P tile [16 i][64 j]
  int qt = blockIdx.x, pair = blockIdx.y, sp = blockIdx.z;
  int src = pair >> 1;
  int tgt = ((pair & 1) == 0) ? (src == 0 ? 1 : 0) : (src == 2 ? 1 : 2);
  const unsigned short* Qh = WSPTR(const unsigned short, O_CORH) + (size_t)src*PP*CC;
  const unsigned short* Ql = WSPTR(const unsigned short, O_CORL) + (size_t)src*PP*CC;
  const unsigned short* Kh = WSPTR(const unsigned short, O_STH)  + (size_t)tgt*PP*CC;
  const unsigned short* Kl = WSPTR(const unsigned short, O_STL)  + (size_t)tgt*PP*CC;
  const unsigned short* Vh = WSPTR(const unsigned short, O_SCH)  + (size_t)tgt*PP*CC;
  const unsigned short* Vl = WSPTR(const unsigned short, O_SCL)  + (size_t)tgt*PP*CC;
  int t = threadIdx.x, lane = t & 63, wid = t >> 6, lr = lane & 15, lk = lane >> 4;

  // Q fragments in registers (B-operand: col=lane&15 = i)
  bf16x8_t qh[8], ql[8];
  int qrow = qt*64 + wid*16 + lr;
  #pragma unroll
  for(int kq = 0; kq < 8; kq++){
    qh[kq] = *(const bf16x8_t*)&Qh[(size_t)qrow*256 + kq*32 + lk*8];
    ql[kq] = *(const bf16x8_t*)&Ql[(size_t)qrow*256 + kq*32 + lk*8];
  }
  float m = -1e38f, lsum = 0.f;
  f32x4_t oacc[16] = {};
  int kt0 = (57*sp)/nspl, kt1 = (57*(sp+1))/nspl;
  int sr = t >> 2, scb = (t & 3)*8;

  for(int kt = kt0; kt < kt1; kt++){
    int j0 = kt*64;
    __syncthreads();
    // stage K [64 j][256 ch] hi+lo, XOR-swizzled 16B chunks
    #pragma unroll
    for(int q = 0; q < 8; q++){
      int ch = scb + q, swz = ch ^ (sr & 7);
      *(bf16x8_t*)&KV[sr*256 + swz*8]         = *(const bf16x8_t*)&Kh[(size_t)(j0+sr)*256 + ch*8];
      *(bf16x8_t*)&KV[16384 + sr*256 + swz*8] = *(const bf16x8_t*)&Kl[(size_t)(j0+sr)*256 + ch*8];
    }
    __syncthreads();
    // QK^T transposed: s[ct] = K_tile . Q  -> D[j_local, i]
    f32x4_t s[4] = {};
    #pragma unroll
    for(int kq = 0; kq < 8; kq++){
      #pragma unroll
      for(int ct = 0; ct < 4; ct++){
        int row = ct*16 + lr;
        int swz = (kq*4 + lk) ^ (lr & 7);
        bf16x8_t kh  = *(const bf16x8_t*)&KV[row*256 + swz*8];
        bf16x8_t klo = *(const bf16x8_t*)&KV[16384 + row*256 + swz*8];
        s[ct] = MFMA16(kh,  qh[kq], s[ct]);
        s[ct] = MFMA16(kh,  ql[kq], s[ct]);
        s[ct] = MFMA16(klo, qh[kq], s[ct]);
      }
    }
    if(kt == 56){  // j >= NP: only first 16 of this tile are valid
      #pragma unroll
      for(int ct = 1; ct < 4; ct++){ s[ct][0] = -1e30f; s[ct][1] = -1e30f; s[ct][2] = -1e30f; s[ct][3] = -1e30f; }
    }
    // online softmax: each lane owns ONE query row (i = lane&15)
    float pmax = s[0][0];
    #pragma unroll
    for(int ct = 0; ct < 4; ct++){
      #pragma unroll
      for(int r = 0; r < 4; r++) pmax = fmaxf(pmax, s[ct][r]);
    }
    pmax = fmaxf(pmax, __shfl_xor(pmax, 16));
    pmax = fmaxf(pmax, __shfl_xor(pmax, 32));
    bool need = pmax > m + 8.f;            // defer-max threshold
    if(__any(need)){
      float mn = need ? pmax : m;
      float sc = __expf(m - mn);
      lsum *= sc;
      #pragma unroll
      for(int c = 0; c < 16; c++){ oacc[c][0]*=sc; oacc[c][1]*=sc; oacc[c][2]*=sc; oacc[c][3]*=sc; }
      m = mn;
    }
    float ps = 0.f;
    #pragma unroll
    for(int ct = 0; ct < 4; ct++){
      float p0 = __expf(s[ct][0]-m), p1 = __expf(s[ct][1]-m);
      float p2 = __expf(s[ct][2]-m), p3 = __expf(s[ct][3]-m);
      ps += (p0+p1) + (p2+p3);
      unsigned short h0,l0,h1,l1,h2,l2,h3,l3;
      split_bf(p0,h0,l0); split_bf(p1,h1,l1); split_bf(p2,h2,l2); split_bf(p3,h3,l3);
      int chunk = ct*2 + (lk>>1);
      int idx = lr*64 + ((chunk ^ (lr&7))*8) + (lk&1)*4;
      uint2 wh = { (unsigned)h0 | ((unsigned)h1<<16), (unsigned)h2 | ((unsigned)h3<<16) };
      uint2 wl = { (unsigned)l0 | ((unsigned)l1<<16), (unsigned)l2 | ((unsigned)l3<<16) };
      *(uint2*)&PBh[wid][idx] = wh;
      *(uint2*)&PBl[wid][idx] = wl;
    }
    ps += __shfl_xor(ps, 16);
    ps += __shfl_xor(ps, 32);
    lsum += ps;
    __syncthreads();
    // stage V [256 c][64 j] hi+lo, XOR-swizzled
    #pragma unroll
    for(int q = 0; q < 8; q++){
      int swz = q ^ (t & 7);
      *(bf16x8_t*)&KV[t*64 + swz*8]         = *(const bf16x8_t*)&Vh[(size_t)t*PP + j0 + q*8];
      *(bf16x8_t*)&KV[16384 + t*64 + swz*8] = *(const bf16x8_t*)&Vl[(size_t)t*PP + j0 + q*8];
    }
    __syncthreads();
    // PV: oacc[c16] += V_tile . P  -> D[c_local, i]
    #pragma unroll
    for(int kk = 0; kk < 2; kk++){
      int pidx = lr*64 + (((kk*4+lk) ^ (lr&7))*8);
      bf16x8_t pah = *(const bf16x8_t*)&PBh[wid][pidx];
      bf16x8_t pal = *(const bf16x8_t*)&PBl[wid][pidx];
      #pragma unroll
      for(int c16 = 0; c16 < 16; c16++){
        int c = c16*16 + lr;
        int vswz = (kk*4 + lk) ^ (lr & 7);
        bf16x8_t vh  = *(const bf16x8_t*)&KV[c*64 + vswz*8];
        bf16x8_t vlo = *(const bf16x8_t*)&KV[16384 + c*64 + vswz*8];
        oacc[c16] = MFMA16(vh,  pah, oacc[c16]);
        oacc[c16] = MFMA16(vh,  pal, oacc[c16]);
        oacc[c16] = MFMA16(vlo, pah, oacc[c16]);
      }
    }
  }
  // store partials (unnormalized O w.r.t. m)
  int idx = (pair*57 + qt)*nspl + sp;
  float* pml = WSPTR(float, O_PML) + (size_t)idx*128;
  float* po  = WSPTR(float, O_PO)  + (size_t)idx*16384;
  int il = wid*16 + lr;
  if(lk == 0){ pml[il] = m; pml[64 + il] = lsum; }
  #pragma unroll
  for(int c16 = 0; c16 < 16; c16++){
    *(f32x4_t*)&po[(size_t)il*256 + c16*16 + lk*4] = oacc[c16];
  }
}

// ---- merge split-K partials, gate, write canvas ----------------------------
__global__ __launch_bounds__(256) void k_merge(char* ws, const float* __restrict__ wgate, int nspl){
  int qt = blockIdx.x, pair = blockIdx.y;
  int src = pair >> 1, cho = (pair & 1)*256;
  unsigned short* cvH = WSPTR(unsigned short, O_CVH) + (size_t)src*CPOS*512 + cho;
  unsigned short* cvL = WSPTR(unsigned short, O_CVL) + (size_t)src*CPOS*512 + cho;
  int t = threadIdx.x, il = t >> 2, cq = (t & 3)*64;
  int base = (pair*57 + qt)*nspl;
  const float* pml = WSPTR(const float, O_PML);
  const float* po  = WSPTR(const float, O_PO);
  float ms[4], ls[4];
  float M = -1e38f;
  for(int s = 0; s < nspl; s++){
    ms[s] = pml[(size_t)(base+s)*128 + il];
    ls[s] = pml[(size_t)(base+s)*128 + 64 + il];
    M = fmaxf(M, ms[s]);
  }
  float L = 0.f;
  float acc[64];
  #pragma unroll
  for(int k = 0; k < 64; k++) acc[k] = 0.f;
  for(int s = 0; s < nspl; s++){
    float w = __expf(ms[s] - M);
    L += ls[s]*w;
    const float* p = &po[(size_t)(base+s)*16384 + (size_t)il*256 + cq];
    #pragma unroll
    for(int k4 = 0; k4 < 16; k4++){
      f32x4_t v = *(const f32x4_t*)&p[k4*4];
      acc[k4*4+0] += v[0]*w; acc[k4*4+1] += v[1]*w;
      acc[k4*4+2] += v[2]*w; acc[k4*4+3] += v[3]*w;
    }
  }
  float invL = 1.f/L, g = 0.f;
  #pragma unroll
  for(int k = 0; k < 64; k++){ acc[k] *= invL; g += wgate[cq+k]*acc[k]; }
  g += __shfl_xor(g, 1);
  g += __shfl_xor(g, 2);
  g = 1.f/(1.f + __expf(-g));
  int i = qt*64 + il;
  if(i < NP){
    int pos = (1 + i/60)*62 + 1 + i%60;
    unsigned short hb[64], lb[64];
    #pragma unroll
    for(int k = 0; k < 64; k++){
      unsigned short h, l; split_bf(acc[k]*g, h, l);
      hb[k] = h; lb[k] = l;
    }
    #pragma unroll
    for(int q = 0; q < 8; q++){
      *(bf16x8_t*)&cvH[(size_t)pos*512 + cq + q*8] = *(const bf16x8_t*)&hb[q*8];
      *(bf16x8_t*)&cvL[(size_t)pos*512 + cq + q*8] = *(const bf16x8_t*)&lb[q*8];
    }
  }
}

// ---- conv3x3 over canvas (512 -> 256), output token-major hi/lo -----------
__global__ __launch_bounds__(256,4) void k_conv(char* ws, const float* __restrict__ bcf){
  __shared__ unsigned short Ah[64*72], Al[64*72], Bh[64*72], Bl[64*72];
  int z = blockIdx.z, y = blockIdx.x, n0 = blockIdx.y*64;
  const unsigned short* cvH = WSPTR(const unsigned short, O_CVH) + (size_t)z*CPOS*512;
  const unsigned short* cvL = WSPTR(const unsigned short, O_CVL) + (size_t)z*CPOS*512;
  const unsigned short* wH = WSPTR(const unsigned short, O_WKH);
  const unsigned short* wL = WSPTR(const unsigned short, O_WKL);
  unsigned short* oH = WSPTR(unsigned short, O_AH) + (size_t)z*PP*CC;
  unsigned short* oL = WSPTR(unsigned short, O_AL) + (size_t)z*PP*CC;
  int lane = threadIdx.x & 63, wid = threadIdx.x >> 6;
  f32x4_t acc[4] = {};
  for(int t = 0; t < 9; t++){
    int posBase = (y + t/3)*62 + (t%3);
    const unsigned short* aH = cvH + (size_t)posBase*512;
    const unsigned short* aL = cvL + (size_t)posBase*512;
    const unsigned short* bH = wH + (size_t)t*131072 + (size_t)n0*512;
    const unsigned short* bL = wL + (size_t)t*131072 + (size_t)n0*512;
    for(int k0 = 0; k0 < 512; k0 += 64){
      __syncthreads();
      stage64(Ah, aH + k0, 512);
      stage64(Al, aL + k0, 512);
      stage64(Bh, bH + k0, 512);
      stage64(Bl, bL + k0, 512);
      __syncthreads();
      mfma64(Ah, Al, Bh, Bl, acc, lane, wid);
    }
  }
  #pragma unroll
  for(int r = 0; r < 4; r++){
    int x = wid*16 + (lane >> 4)*4 + r;
    if(x >= 60) continue;
    int i = y*60 + x;
    #pragma unroll
    for(int ct = 0; ct < 4; ct++){
      int c = n0 + ct*16 + (lane & 15);
      float v = acc[ct][r] + bcf[c];
      unsigned short h, l; split_bf(v, h, l);
      oH[(size_t)i*CC + c] = h; oL[(size_t)i*CC + c] = l;
    }
  }
}

// ---- GRU gates -------------------------------------------------------------
__global__ __launch_bounds__(256,4) void k_gates(char* ws, const float* __restrict__ bu, const float* __restrict__ br){
  __shared__ unsigned short Ah[64*72], Al[64*72], Bh[64*72], Bl[64*72];
  int z = blockIdx.z, m0 = blockIdx.x*64, n0 = blockIdx.y*64;
  const unsigned short* aH0 = WSPTR(const unsigned short, O_AH)  + (size_t)z*PP*CC;
  const unsigned short* aL0 = WSPTR(const unsigned short, O_AL)  + (size_t)z*PP*CC;
  const unsigned short* aH1 = WSPTR(const unsigned short, O_STH) + (size_t)z*PP*CC;
  const unsigned short* aL1 = WSPTR(const unsigned short, O_STL) + (size_t)z*PP*CC;
  const unsigned short* bH  = WSPTR(const unsigned short, O_WURH) + (size_t)n0*512;
  const unsigned short* bL  = WSPTR(const unsigned short, O_WURL) + (size_t)n0*512;
  const float* prevF = WSPTR(const float, O_SF) + (size_t)z*PP*CC;
  float* uOut = WSPTR(float, O_U) + (size_t)z*PP*CC;
  unsigned short* prH = WSPTR(unsigned short, O_PRH) + (size_t)z*PP*CC;
  unsigned short* prL = WSPTR(unsigned short, O_PRL) + (size_t)z*PP*CC;
  int lane = threadIdx.x & 63, wid = threadIdx.x >> 6;
  f32x4_t acc[4] = {};
  for(int ks = 0; ks < 8; ks++){
    const unsigned short* sah = (ks < 4) ? aH0 : aH1;
    const unsigned short* sal = (ks < 4) ? aL0 : aL1;
    int koff = (ks & 3) * 64;
    __syncthreads();
    stage64(Ah, sah + (size_t)m0*256 + koff, 256);
    stage64(Al, sal + (size_t)m0*256 + koff, 256);
    stage64(Bh, bH + ks*64, 512);
    stage64(Bl, bL + ks*64, 512);
    __syncthreads();
    mfma64(Ah, Al, Bh, Bl, acc, lane, wid);
  }
  #pragma unroll
  for(int r = 0; r < 4; r++){
    int i = m0 + wid*16 + (lane >> 4)*4 + r;
    if(i >= NP) continue;
    #pragma unroll
    for(int ct = 0; ct < 4; ct++){
      int c = n0 + ct*16 + (lane & 15);
      float pre = acc[ct][r] + (c < 256 ? bu[c] : br[c - 256]);
      float sg = 1.f / (1.f + __expf(-pre));
      if(c < 256){
        uOut[(size_t)i*CC + c] = sg;
      } else {
        int e = c - 256;
        float pv = prevF[(size_t)i*CC + e];
        unsigned short h, l; split_bf(sg * pv, h, l);
        prH[(size_t)i*CC + e] = h; prL[(size_t)i*CC + e] = l;
      }
    }
  }
}

// ---- GRU out ---------------------------------------------------------------
__global__ __launch_bounds__(256,4) void k_gruo(char* ws, const float* __restrict__ bo, float* __restrict__ dout, int fin){
  __shared__ unsigned short Ah[64*72], Al[64*72], Bh[64*72], Bl[64*72];
  int z = blockIdx.z, m0 = blockIdx.x*64, n0 = blockIdx.y*64;
  const unsigned short* aH0 = WSPTR(const unsigned short, O_AH)  + (size_t)z*PP*CC;
  const unsigned short* aL0 = WSPTR(const unsigned short, O_AL)  + (size_t)z*PP*CC;
  const unsigned short* aH1 = WSPTR(const unsigned short, O_PRH) + (size_t)z*PP*CC;
  const unsigned short* aL1 = WSPTR(const unsigned short, O_PRL) + (size_t)z*PP*CC;
  const unsigned short* bH  = WSPTR(const unsigned short, O_WOH) + (size_t)n0*512;
  const unsigned short* bL  = WSPTR(const unsigned short, O_WOL) + (size_t)n0*512;
  const float* uBuf = WSPTR(const float, O_U) + (size_t)z*PP*CC;
  float* sF = WSPTR(float, O_SF) + (size_t)z*PP*CC;
  unsigned short* sTh = WSPTR(unsigned short, O_STH) + (size_t)z*PP*CC;
  unsigned short* sTl = WSPTR(unsigned short, O_STL) + (size_t)z*PP*CC;
  unsigned short* sCh = WSPTR(unsigned short, O_SCH) + (size_t)z*PP*CC;
  unsigned short* sCl = WSPTR(unsigned short, O_SCL) + (size_t)z*PP*CC;
  int lane = threadIdx.x & 63, wid = threadIdx.x >> 6;
  f32x4_t acc[4] = {};
  for(int ks = 0; ks < 8; ks++){
    const unsigned short* sah = (ks < 4) ? aH0 : aH1;
    const unsigned short* sal = (ks < 4) ? aL0 : aL1;
    int koff = (ks & 3) * 64;
    __syncthreads();
    stage64(Ah, sah + (size_t)m0*256 + koff, 256);
    stage64(Al, sal + (size_t)m0*256 + koff, 256);
    stage64(Bh, bH + ks*64, 512);
    stage64(Bl, bL + ks*64, 512);
    __syncthreads();
    mfma64(Ah, Al, Bh, Bl, acc, lane, wid);
  }
  #pragma unroll
  for(int r = 0; r < 4; r++){
    int i = m0 + wid*16 + (lane >> 4)*4 + r;
    if(i >= NP) continue;
    #pragma unroll
    for(int ct = 0; ct < 4; ct++){
      int c = n0 + ct*16 + (lane & 15);
      float o = tanhf(acc[ct][r] + bo[c]);
      float uu = uBuf[(size_t)i*CC + c];
      float pv = sF[(size_t)i*CC + c];
      float h = pv*(1.f - uu) + o*uu;
      if(fin){
        dout[(size_t)z*921600 + (size_t)c*3600 + i] = h;
      } else {
        sF[(size_t)i*CC + c] = h;
        unsigned short hh, hl; split_bf(h, hh, hl);
        sTh[(size_t)i*CC + c] = hh; sTl[(size_t)i*CC + c] = hl;
        sCh[(size_t)c*PP + i] = hh; sCl[(size_t)c*PP + i] = hl;
      }
    }
  }
}

extern "C" void kernel_launch(void* const* d_in, const int* in_sizes, int n_in,
                              void* d_out, int out_size, void* d_ws, size_t ws_size,
                              hipStream_t stream){
  char* ws = (char*)d_ws;
  const float* in1   = (const float*)d_in[0];
  const float* in2   = (const float*)d_in[1];
  const float* in3   = (const float*)d_in[2];
  const float* Wlin  = (const float*)d_in[3];
  const float* Wgate = (const float*)d_in[4];
  const float* Wcf   = (const float*)d_in[5];
  const float* bcf   = (const float*)d_in[6];
  const float* Wr    = (const float*)d_in[7];
  const float* br_   = (const float*)d_in[8];
  const float* Wu    = (const float*)d_in[9];
  const float* bu_   = (const float*)d_in[10];
  const float* Wo    = (const float*)d_in[11];
  const float* bo_   = (const float*)d_in[12];

  // split-K factor limited by available workspace
  int nspl = 3;
  while(nspl > 1 && O_PO + (size_t)342*nspl*65536 > ws_size) nspl--;

  k_zero<<<dim3(2048), dim3(256), 0, stream>>>(ws);
  k_weights<<<dim3(1024), dim3(256), 0, stream>>>(ws, Wlin, Wu, Wr, Wo, Wcf);
  k_transpose<<<dim3(57, 4, 3), dim3(256), 0, stream>>>(ws, in1, in2, in3);

  for(int rd = 0; rd < 5; rd++){
    k_corr <<<dim3(57, 4, 3), dim3(256), 0, stream>>>(ws);
    k_flash<<<dim3(57, 6, nspl), dim3(256), 0, stream>>>(ws, nspl);
    k_merge<<<dim3(57, 6), dim3(256), 0, stream>>>(ws, Wgate, nspl);
    k_conv <<<dim3(60, 4, 3), dim3(256), 0, stream>>>(ws, bcf);
    k_gates<<<dim3(57, 8, 3), dim3(256), 0, stream>>>(ws, bu_, br_);
    k_gruo <<<dim3(57, 4, 3), dim3(256), 0, stream>>>(ws, bo_, (float*)d_out, rd == 4 ? 1 : 0);
  }
}

// Round 3
// 2737.422 us; speedup vs baseline: 1.8937x; 1.8937x over previous
//
#include <hip/hip_runtime.h>

typedef float f32x4_t __attribute__((ext_vector_type(4)));
typedef short bf16x8_t __attribute__((ext_vector_type(8)));

#define MFMA16(A,B,C) __builtin_amdgcn_mfma_f32_16x16x32_bf16((A),(B),(C),0,0,0)

static constexpr int CC = 256;      // channels
static constexpr int NP = 3600;     // valid tokens
static constexpr int PP = 3648;     // padded tokens (57*64)
static constexpr int CPOS = 3906;   // canvas positions (62*63, incl. slack)

static constexpr size_t SZ_F  = (size_t)PP*CC*4;
static constexpr size_t SZ_H  = (size_t)PP*CC*2;
static constexpr size_t SZ_CV = (size_t)CPOS*512*2;

static constexpr size_t O_SF   = 0;
static constexpr size_t O_STH  = O_SF   + 3*SZ_F;
static constexpr size_t O_STL  = O_STH  + 3*SZ_H;
static constexpr size_t O_SCH  = O_STL  + 3*SZ_H;
static constexpr size_t O_SCL  = O_SCH  + 3*SZ_H;
static constexpr size_t O_CORH = O_SCL  + 3*SZ_H;
static constexpr size_t O_CORL = O_CORH + 3*SZ_H;
static constexpr size_t O_CVH  = O_CORL + 3*SZ_H;
static constexpr size_t O_CVL  = O_CVH  + 3*SZ_CV;
static constexpr size_t O_WLH  = O_CVL  + 3*SZ_CV;
static constexpr size_t O_WLL  = O_WLH  + 131072;
static constexpr size_t O_WURH = O_WLL  + 131072;
static constexpr size_t O_WURL = O_WURH + 524288;
static constexpr size_t O_WOH  = O_WURL + 524288;
static constexpr size_t O_WOL  = O_WOH  + 262144;
static constexpr size_t O_WKH  = O_WOL  + 262144;
static constexpr size_t O_WKL  = O_WKH  + 2359296;
// X region: flash partials (flash->merge) OVERLAID with AH/AL/U/PRH/PRL (conv->gruo)
static constexpr size_t O_X    = O_WKL  + 2359296;
static constexpr size_t O_PML  = O_X;                 // 342*nspl*512 B
static constexpr size_t O_PO   = O_X + 1048576;       // 342*nspl*65536 B
static constexpr size_t O_AH   = O_X;
static constexpr size_t O_AL   = O_AH + 3*SZ_H;
static constexpr size_t O_U    = O_AL + 3*SZ_H;
static constexpr size_t O_PRH  = O_U  + 3*SZ_F;
static constexpr size_t O_PRL  = O_PRH + 3*SZ_H;

#define WSPTR(T, OFF) ((T*)(ws + (OFF)))

__device__ __forceinline__ unsigned short f2bf(float f){
  unsigned u = __builtin_bit_cast(unsigned, f);
  u += 0x7FFFu + ((u >> 16) & 1u);
  return (unsigned short)(u >> 16);
}
__device__ __forceinline__ float bf2f(unsigned short h){
  unsigned u = ((unsigned)h) << 16;
  return __builtin_bit_cast(float, u);
}
__device__ __forceinline__ void split_bf(float x, unsigned short &h, unsigned short &l){
  h = f2bf(x);
  l = f2bf(x - bf2f(h));
}

// async global->LDS, 16B per lane, LDS dest = wave-uniform base + lane*16
__device__ __forceinline__ void gll16(const void* g, void* l){
  __builtin_amdgcn_global_load_lds(
      (const __attribute__((address_space(1))) unsigned*)g,
      (__attribute__((address_space(3))) unsigned*)l, 16, 0, 0);
}

// ---- shared GEMM pieces for corr/conv/gru: 64x64 tile, LDS stride 72 ------
// coalesced: 8 lanes cover 128B contiguous per row, 8 rows per instruction
__device__ __forceinline__ void stage64(unsigned short* dst, const unsigned short* __restrict__ src, int ld){
  int t = threadIdx.x, r0 = t >> 3, c8 = (t & 7) * 8;
  #pragma unroll
  for(int h = 0; h < 2; h++){
    int r = r0 + h*32;
    *(bf16x8_t*)&dst[r*72 + c8] = *(const bf16x8_t*)&src[(size_t)r*ld + c8];
  }
}

__device__ __forceinline__ void mfma64(const unsigned short* Ah, const unsigned short* Al,
                                       const unsigned short* Bh, const unsigned short* Bl,
                                       f32x4_t acc[4], int lane, int wid){
  int kb = (lane >> 4) * 8, lr = lane & 15;
  int arow = wid*16 + lr;
  #pragma unroll
  for(int kk = 0; kk < 2; kk++){
    bf16x8_t ah = *(const bf16x8_t*)&Ah[arow*72 + kk*32 + kb];
    bf16x8_t al = *(const bf16x8_t*)&Al[arow*72 + kk*32 + kb];
    #pragma unroll
    for(int ct = 0; ct < 4; ct++){
      int brow = ct*16 + lr;
      bf16x8_t bh = *(const bf16x8_t*)&Bh[brow*72 + kk*32 + kb];
      bf16x8_t bl = *(const bf16x8_t*)&Bl[brow*72 + kk*32 + kb];
      acc[ct] = MFMA16(ah, bh, acc[ct]);
      acc[ct] = MFMA16(ah, bl, acc[ct]);
      acc[ct] = MFMA16(al, bh, acc[ct]);
    }
  }
}

// ---- zero canvases --------------------------------------------------------
__global__ void k_zero(char* ws){
  size_t n = (6*SZ_CV)/16;
  uint4* p = (uint4*)(ws + O_CVH);
  uint4 z = {0,0,0,0};
  for(size_t x = (size_t)blockIdx.x*256 + threadIdx.x; x < n; x += (size_t)gridDim.x*256) p[x] = z;
}

// ---- split weights --------------------------------------------------------
__global__ void k_weights(char* ws, const float* __restrict__ Wlin, const float* __restrict__ Wup,
                          const float* __restrict__ Wrs, const float* __restrict__ Wo,
                          const float* __restrict__ Wcf){
  const size_t N1 = 65536, N2 = N1 + 262144, N3 = N2 + 131072, N4 = N3 + 1179648;
  for(size_t x = (size_t)blockIdx.x*256 + threadIdx.x; x < N4; x += (size_t)gridDim.x*256){
    float v; unsigned short *dh, *dl; size_t off;
    if(x < N1){
      v = Wlin[x]; dh = WSPTR(unsigned short, O_WLH); dl = WSPTR(unsigned short, O_WLL); off = x;
    } else if(x < N2){
      size_t i = x - N1; int e = (int)(i >> 9), c = (int)(i & 511);
      v = (e < 256) ? Wup[(size_t)e*512 + c] : Wrs[(size_t)(e-256)*512 + c];
      dh = WSPTR(unsigned short, O_WURH); dl = WSPTR(unsigned short, O_WURL); off = i;
    } else if(x < N3){
      size_t i = x - N2; v = Wo[i];
      dh = WSPTR(unsigned short, O_WOH); dl = WSPTR(unsigned short, O_WOL); off = i;
    } else {
      size_t i = x - N3; int t = (int)(i % 9); size_t rest = i / 9;
      int ic = (int)(rest & 511), o = (int)(rest >> 9);
      v = Wcf[i]; off = (size_t)t*131072 + (size_t)o*512 + ic;
      dh = WSPTR(unsigned short, O_WKH); dl = WSPTR(unsigned short, O_WKL);
    }
    unsigned short h, l; split_bf(v, h, l);
    dh[off] = h; dl[off] = l;
  }
}

// ---- transpose inputs to token-major + make bf16 copies -------------------
__global__ __launch_bounds__(256) void k_transpose(char* ws, const float* __restrict__ in0,
                                                   const float* __restrict__ in1, const float* __restrict__ in2){
  __shared__ float tile[64*65];
  int z = blockIdx.z;
  const float* in = z == 0 ? in0 : (z == 1 ? in1 : in2);
  int p0 = blockIdx.x*64, c0 = blockIdx.y*64;
  float* sF = WSPTR(float, O_SF) + (size_t)z*PP*CC;
  unsigned short* sTh = WSPTR(unsigned short, O_STH) + (size_t)z*PP*CC;
  unsigned short* sTl = WSPTR(unsigned short, O_STL) + (size_t)z*PP*CC;
  unsigned short* sCh = WSPTR(unsigned short, O_SCH) + (size_t)z*PP*CC;
  unsigned short* sCl = WSPTR(unsigned short, O_SCL) + (size_t)z*PP*CC;
  int t = threadIdx.x, pl = t & 63, cq = t >> 6;
  #pragma unroll
  for(int rr = 0; rr < 16; rr++){
    int cl = rr*4 + cq, p = p0 + pl, c = c0 + cl;
    float v = (p < NP) ? in[(size_t)c*NP + p] : 0.f;
    tile[cl*65 + pl] = v;
    if(p < NP){
      unsigned short h, l; split_bf(v, h, l);
      sCh[(size_t)c*PP + p] = h; sCl[(size_t)c*PP + p] = l;
    }
  }
  __syncthreads();
  #pragma unroll
  for(int rr = 0; rr < 16; rr++){
    int prow = rr*4 + cq, p = p0 + prow, cl = pl;
    if(p < NP){
      float v = tile[cl*65 + prow];
      int c = c0 + cl;
      sF[(size_t)p*CC + c] = v;
      unsigned short h, l; split_bf(v, h, l);
      sTh[(size_t)p*CC + c] = h; sTl[(size_t)p*CC + c] = l;
    }
  }
}

// ---- corr = stateT @ W_lin^T ----------------------------------------------
__global__ __launch_bounds__(256,4) void k_corr(char* ws){
  __shared__ unsigned short Ah[64*72], Al[64*72], Bh[64*72], Bl[64*72];
  int z = blockIdx.z, m0 = blockIdx.x*64, n0 = blockIdx.y*64;
  const unsigned short* aH = WSPTR(const unsigned short, O_STH) + (size_t)z*PP*CC;
  const unsigned short* aL = WSPTR(const unsigned short, O_STL) + (size_t)z*PP*CC;
  const unsigned short* bH = WSPTR(const unsigned short, O_WLH);
  const unsigned short* bL = WSPTR(const unsigned short, O_WLL);
  unsigned short* cH = WSPTR(unsigned short, O_CORH) + (size_t)z*PP*CC;
  unsigned short* cL = WSPTR(unsigned short, O_CORL) + (size_t)z*PP*CC;
  int lane = threadIdx.x & 63, wid = threadIdx.x >> 6;
  f32x4_t acc[4] = {};
  for(int k0 = 0; k0 < 256; k0 += 64){
    __syncthreads();
    stage64(Ah, aH + (size_t)m0*256 + k0, 256);
    stage64(Al, aL + (size_t)m0*256 + k0, 256);
    stage64(Bh, bH + (size_t)n0*256 + k0, 256);
    stage64(Bl, bL + (size_t)n0*256 + k0, 256);
    __syncthreads();
    mfma64(Ah, Al, Bh, Bl, acc, lane, wid);
  }
  #pragma unroll
  for(int r = 0; r < 4; r++){
    int i = m0 + wid*16 + (lane >> 4)*4 + r;
    if(i >= NP) continue;
    #pragma unroll
    for(int ct = 0; ct < 4; ct++){
      int c = n0 + ct*16 + (lane & 15);
      unsigned short h, l; split_bf(acc[ct][r], h, l);
      cH[(size_t)i*CC + c] = h; cL[(size_t)i*CC + c] = l;
    }
  }
}

// ---- split-K flash attention (S^T orientation), gload_lds staging ---------
__global__ __launch_bounds__(256,2) void k_flash(char* ws, int nspl){
  __shared__ unsigned short KV[32768];                  // 64KB: Q / K [64][256] h|l, then V [256][64] h|l
  __shared__ unsigned short PBh[4][1024], PBl[4][1024]; // per-wave P tile [16 i][64 j]
  int qt = blockIdx.x, pair = blockIdx.y, sp = blockIdx.z;
  int src = pair >> 1;
  int tgt = ((pair & 1) == 0) ? (src == 0 ? 1 : 0) : (src == 2 ? 1 : 2);
  const unsigned short* Qh = WSPTR(const unsigned short, O_CORH) + (size_t)src*PP*CC;
  const unsigned short* Ql = WSPTR(const unsigned short, O_CORL) + (size_t)src*PP*CC;
  const unsigned short* Kh = WSPTR(const unsigned short, O_STH)  + (size_t)tgt*PP*CC;
  const unsigned short* Kl = WSPTR(const unsigned short, O_STL)  + (size_t)tgt*PP*CC;
  const unsigned short* Vh = WSPTR(const unsigned short, O_SCH)  + (size_t)tgt*PP*CC;
  const unsigned short* Vl = WSPTR(const unsigned short, O_SCL)  + (size_t)tgt*PP*CC;
  int t = threadIdx.x, lane = t & 63, wid = t >> 6, lr = lane & 15, lk = lane >> 4;
  int rowi = lane >> 5, c_lds = lane & 31;   // K/Q stage mapping (2 rows x 32 chunks / instr)
  int vrow8 = lane >> 3, vj = lane & 7;      // V stage mapping (8 rows x 8 chunks / instr)

  // ---- stage Q tile [64][256] hi+lo, pre-swizzled source, then frags ------
  #pragma unroll
  for(int q = 0; q < 8; q++){
    int n = wid*8 + q;
    int row = 2*n + rowi;
    int gch = c_lds ^ (row & 7);
    size_t ga = (size_t)(qt*64 + row)*256 + gch*8;
    gll16(&Qh[ga], &KV[n*512]);
    gll16(&Ql[ga], &KV[16384 + n*512]);
  }
  asm volatile("s_waitcnt vmcnt(0)" ::: "memory");
  __syncthreads();
  bf16x8_t qh[8], ql[8];
  {
    int qr = wid*16 + lr;
    #pragma unroll
    for(int kq = 0; kq < 8; kq++){
      int ch = (kq*4 + lk) ^ (lr & 7);
      qh[kq] = *(const bf16x8_t*)&KV[qr*256 + ch*8];
      ql[kq] = *(const bf16x8_t*)&KV[16384 + qr*256 + ch*8];
    }
  }
  __syncthreads();  // all waves done reading Q before K overwrites

  float m = -1e38f, lsum = 0.f;
  f32x4_t oacc[16] = {};
  int kt0 = (57*sp)/nspl, kt1 = (57*(sp+1))/nspl;

  for(int kt = kt0; kt < kt1; kt++){
    int j0 = kt*64;
    // ---- stage K [64 j][256 ch] hi+lo ----
    #pragma unroll
    for(int q = 0; q < 8; q++){
      int n = wid*8 + q;
      int row = 2*n + rowi;
      int gch = c_lds ^ (row & 7);
      size_t ga = (size_t)(j0 + row)*256 + gch*8;
      gll16(&Kh[ga], &KV[n*512]);
      gll16(&Kl[ga], &KV[16384 + n*512]);
    }
    asm volatile("s_waitcnt vmcnt(0)" ::: "memory");
    __syncthreads();
    // ---- QK^T (transposed): s[ct] = K_tile . Q -> D[j_local, i=lr] ----
    f32x4_t s[4] = {};
    __builtin_amdgcn_s_setprio(1);
    #pragma unroll
    for(int kq = 0; kq < 8; kq++){
      #pragma unroll
      for(int ct = 0; ct < 4; ct++){
        int row = ct*16 + lr;
        int ch = (kq*4 + lk) ^ (lr & 7);
        bf16x8_t khv = *(const bf16x8_t*)&KV[row*256 + ch*8];
        bf16x8_t klv = *(const bf16x8_t*)&KV[16384 + row*256 + ch*8];
        s[ct] = MFMA16(khv, qh[kq], s[ct]);
        s[ct] = MFMA16(khv, ql[kq], s[ct]);
        s[ct] = MFMA16(klv, qh[kq], s[ct]);
      }
    }
    __builtin_amdgcn_s_setprio(0);
    if(kt == 56){  // j >= NP: only first 16 rows of this tile valid
      #pragma unroll
      for(int ct = 1; ct < 4; ct++){ s[ct][0] = -1e30f; s[ct][1] = -1e30f; s[ct][2] = -1e30f; s[ct][3] = -1e30f; }
    }
    // ---- online softmax: each lane owns ONE query row (i = lane&15) ----
    float pmax = s[0][0];
    #pragma unroll
    for(int ct = 0; ct < 4; ct++){
      #pragma unroll
      for(int r = 0; r < 4; r++) pmax = fmaxf(pmax, s[ct][r]);
    }
    pmax = fmaxf(pmax, __shfl_xor(pmax, 16));
    pmax = fmaxf(pmax, __shfl_xor(pmax, 32));
    bool need = pmax > m + 8.f;            // defer-max threshold
    if(__any(need)){
      float mn = need ? pmax : m;
      float sc = __expf(m - mn);
      lsum *= sc;
      #pragma unroll
      for(int c = 0; c < 16; c++){ oacc[c][0]*=sc; oacc[c][1]*=sc; oacc[c][2]*=sc; oacc[c][3]*=sc; }
      m = mn;
    }
    float ps = 0.f;
    float pv[16];
    #pragma unroll
    for(int ct = 0; ct < 4; ct++){
      pv[ct*4+0] = __expf(s[ct][0]-m); pv[ct*4+1] = __expf(s[ct][1]-m);
      pv[ct*4+2] = __expf(s[ct][2]-m); pv[ct*4+3] = __expf(s[ct][3]-m);
      ps += (pv[ct*4+0]+pv[ct*4+1]) + (pv[ct*4+2]+pv[ct*4+3]);
    }
    ps += __shfl_xor(ps, 16);
    ps += __shfl_xor(ps, 32);
    lsum += ps;
    __syncthreads();   // K reads done by all waves -> buffer free for V
    // ---- issue V stage [256 c][64 j] hi+lo (flies during P store) ----
    #pragma unroll
    for(int q = 0; q < 8; q++){
      int n = wid*8 + q;
      int row = 8*n + vrow8;
      int gch = vj ^ (row & 7);
      size_t ga = (size_t)row*PP + j0 + gch*8;
      gll16(&Vh[ga], &KV[n*512]);
      gll16(&Vl[ga], &KV[16384 + n*512]);
    }
    // ---- P store to per-wave LDS while V loads fly ----
    #pragma unroll
    for(int ct = 0; ct < 4; ct++){
      unsigned short h0,l0,h1,l1,h2,l2,h3,l3;
      split_bf(pv[ct*4+0],h0,l0); split_bf(pv[ct*4+1],h1,l1);
      split_bf(pv[ct*4+2],h2,l2); split_bf(pv[ct*4+3],h3,l3);
      int chunk = ct*2 + (lk>>1);
      int idx = lr*64 + ((chunk ^ (lr&7))*8) + (lk&1)*4;
      uint2 wh = { (unsigned)h0 | ((unsigned)h1<<16), (unsigned)h2 | ((unsigned)h3<<16) };
      uint2 wl = { (unsigned)l0 | ((unsigned)l1<<16), (unsigned)l2 | ((unsigned)l3<<16) };
      *(uint2*)&PBh[wid][idx] = wh;
      *(uint2*)&PBl[wid][idx] = wl;
    }
    asm volatile("s_waitcnt vmcnt(0)" ::: "memory");
    __syncthreads();
    // ---- PV: oacc[c16] += V_tile . P -> D[c_local, i=lr] ----
    __builtin_amdgcn_s_setprio(1);
    #pragma unroll
    for(int kk = 0; kk < 2; kk++){
      int pidx = lr*64 + (((kk*4+lk) ^ (lr&7))*8);
      bf16x8_t pah = *(const bf16x8_t*)&PBh[wid][pidx];
      bf16x8_t pal = *(const bf16x8_t*)&PBl[wid][pidx];
      #pragma unroll
      for(int c16 = 0; c16 < 16; c16++){
        int c = c16*16 + lr;
        int ch = (kk*4 + lk) ^ (lr & 7);
        bf16x8_t vh  = *(const bf16x8_t*)&KV[c*64 + ch*8];
        bf16x8_t vlo = *(const bf16x8_t*)&KV[16384 + c*64 + ch*8];
        oacc[c16] = MFMA16(vh,  pah, oacc[c16]);
        oacc[c16] = MFMA16(vh,  pal, oacc[c16]);
        oacc[c16] = MFMA16(vlo, pah, oacc[c16]);
      }
    }
    __builtin_amdgcn_s_setprio(0);
    __syncthreads();   // V reads done before next K stage
  }
  // ---- store partials (unnormalized O w.r.t. m) ----
  int idx = (pair*57 + qt)*nspl + sp;
  float* pml = WSPTR(float, O_PML) + (size_t)idx*128;
  float* po  = WSPTR(float, O_PO)  + (size_t)idx*16384;
  int il = wid*16 + lr;
  if(lk == 0){ pml[il] = m; pml[64 + il] = lsum; }
  #pragma unroll
  for(int c16 = 0; c16 < 16; c16++){
    *(f32x4_t*)&po[(size_t)il*256 + c16*16 + lk*4] = oacc[c16];
  }
}

// ---- merge split-K partials, gate, write canvas ----------------------------
__global__ __launch_bounds__(256) void k_merge(char* ws, const float* __restrict__ wgate, int nspl){
  int qt = blockIdx.x, pair = blockIdx.y;
  int src = pair >> 1, cho = (pair & 1)*256;
  unsigned short* cvH = WSPTR(unsigned short, O_CVH) + (size_t)src*CPOS*512 + cho;
  unsigned short* cvL = WSPTR(unsigned short, O_CVL) + (size_t)src*CPOS*512 + cho;
  int t = threadIdx.x, il = t >> 2, q4 = t & 3;
  int base = (pair*57 + qt)*nspl;
  const float* pml = WSPTR(const float, O_PML);
  const float* po  = WSPTR(const float, O_PO);
  float M = -1e38f;
  for(int s = 0; s < nspl; s++) M = fmaxf(M, pml[(size_t)(base+s)*128 + il]);
  float L = 0.f;
  float acc[64];
  #pragma unroll
  for(int k = 0; k < 64; k++) acc[k] = 0.f;
  for(int s = 0; s < nspl; s++){
    float w = __expf(pml[(size_t)(base+s)*128 + il] - M);
    L += pml[(size_t)(base+s)*128 + 64 + il]*w;
    const float* p = &po[(size_t)(base+s)*16384 + (size_t)il*256];
    #pragma unroll
    for(int k4 = 0; k4 < 16; k4++){
      f32x4_t v = *(const f32x4_t*)&p[k4*16 + q4*4];  // quarter-wave covers 64B contiguous
      acc[k4*4+0] += v[0]*w; acc[k4*4+1] += v[1]*w;
      acc[k4*4+2] += v[2]*w; acc[k4*4+3] += v[3]*w;
    }
  }
  float invL = 1.f/L, g = 0.f;
  #pragma unroll
  for(int k4 = 0; k4 < 16; k4++){
    #pragma unroll
    for(int e = 0; e < 4; e++){
      acc[k4*4+e] *= invL;
      g += wgate[k4*16 + q4*4 + e] * acc[k4*4+e];
    }
  }
  g += __shfl_xor(g, 1);
  g += __shfl_xor(g, 2);
  g = 1.f/(1.f + __expf(-g));
  int i = qt*64 + il;
  if(i < NP){
    int pos = (1 + i/60)*62 + 1 + i%60;
    #pragma unroll
    for(int k4 = 0; k4 < 16; k4++){
      unsigned short h0,l0,h1,l1,h2,l2,h3,l3;
      split_bf(acc[k4*4+0]*g, h0, l0); split_bf(acc[k4*4+1]*g, h1, l1);
      split_bf(acc[k4*4+2]*g, h2, l2); split_bf(acc[k4*4+3]*g, h3, l3);
      uint2 wh = { (unsigned)h0 | ((unsigned)h1<<16), (unsigned)h2 | ((unsigned)h3<<16) };
      uint2 wl = { (unsigned)l0 | ((unsigned)l1<<16), (unsigned)l2 | ((unsigned)l3<<16) };
      *(uint2*)&cvH[(size_t)pos*512 + k4*16 + q4*4] = wh;
      *(uint2*)&cvL[(size_t)pos*512 + k4*16 + q4*4] = wl;
    }
  }
}

// ---- conv3x3 over canvas (512 -> 256), output token-major hi/lo -----------
__global__ __launch_bounds__(256,4) void k_conv(char* ws, const float* __restrict__ bcf){
  __shared__ unsigned short Ah[64*72], Al[64*72], Bh[64*72], Bl[64*72];
  int z = blockIdx.z, y = blockIdx.x, n0 = blockIdx.y*64;
  const unsigned short* cvH = WSPTR(const unsigned short, O_CVH) + (size_t)z*CPOS*512;
  const unsigned short* cvL = WSPTR(const unsigned short, O_CVL) + (size_t)z*CPOS*512;
  const unsigned short* wH = WSPTR(const unsigned short, O_WKH);
  const unsigned short* wL = WSPTR(const unsigned short, O_WKL);
  unsigned short* oH = WSPTR(unsigned short, O_AH) + (size_t)z*PP*CC;
  unsigned short* oL = WSPTR(unsigned short, O_AL) + (size_t)z*PP*CC;
  int lane = threadIdx.x & 63, wid = threadIdx.x >> 6;
  f32x4_t acc[4] = {};
  for(int t = 0; t < 9; t++){
    int posBase = (y + t/3)*62 + (t%3);
    const unsigned short* aH = cvH + (size_t)posBase*512;
    const unsigned short* aL = cvL + (size_t)posBase*512;
    const unsigned short* bH = wH + (size_t)t*131072 + (size_t)n0*512;
    const unsigned short* bL = wL + (size_t)t*131072 + (size_t)n0*512;
    for(int k0 = 0; k0 < 512; k0 += 64){
      __syncthreads();
      stage64(Ah, aH + k0, 512);
      stage64(Al, aL + k0, 512);
      stage64(Bh, bH + k0, 512);
      stage64(Bl, bL + k0, 512);
      __syncthreads();
      mfma64(Ah, Al, Bh, Bl, acc, lane, wid);
    }
  }
  #pragma unroll
  for(int r = 0; r < 4; r++){
    int x = wid*16 + (lane >> 4)*4 + r;
    if(x >= 60) continue;
    int i = y*60 + x;
    #pragma unroll
    for(int ct = 0; ct < 4; ct++){
      int c = n0 + ct*16 + (lane & 15);
      float v = acc[ct][r] + bcf[c];
      unsigned short h, l; split_bf(v, h, l);
      oH[(size_t)i*CC + c] = h; oL[(size_t)i*CC + c] = l;
    }
  }
}

// ---- GRU gates -------------------------------------------------------------
__global__ __launch_bounds__(256,4) void k_gates(char* ws, const float* __restrict__ bu, const float* __restrict__ br){
  __shared__ unsigned short Ah[64*72], Al[64*72], Bh[64*72], Bl[64*72];
  int z = blockIdx.z, m0 = blockIdx.x*64, n0 = blockIdx.y*64;
  const unsigned short* aH0 = WSPTR(const unsigned short, O_AH)  + (size_t)z*PP*CC;
  const unsigned short* aL0 = WSPTR(const unsigned short, O_AL)  + (size_t)z*PP*CC;
  const unsigned short* aH1 = WSPTR(const unsigned short, O_STH) + (size_t)z*PP*CC;
  const unsigned short* aL1 = WSPTR(const unsigned short, O_STL) + (size_t)z*PP*CC;
  const unsigned short* bH  = WSPTR(const unsigned short, O_WURH) + (size_t)n0*512;
  const unsigned short* bL  = WSPTR(const unsigned short, O_WURL) + (size_t)n0*512;
  const float* prevF = WSPTR(const float, O_SF) + (size_t)z*PP*CC;
  float* uOut = WSPTR(float, O_U) + (size_t)z*PP*CC;
  unsigned short* prH = WSPTR(unsigned short, O_PRH) + (size_t)z*PP*CC;
  unsigned short* prL = WSPTR(unsigned short, O_PRL) + (size_t)z*PP*CC;
  int lane = threadIdx.x & 63, wid = threadIdx.x >> 6;
  f32x4_t acc[4] = {};
  for(int ks = 0; ks < 8; ks++){
    const unsigned short* sah = (ks < 4) ? aH0 : aH1;
    const unsigned short* sal = (ks < 4) ? aL0 : aL1;
    int koff = (ks & 3) * 64;
    __syncthreads();
    stage64(Ah, sah + (size_t)m0*256 + koff, 256);
    stage64(Al, sal + (size_t)m0*256 + koff, 256);
    stage64(Bh, bH + ks*64, 512);
    stage64(Bl, bL + ks*64, 512);
    __syncthreads();
    mfma64(Ah, Al, Bh, Bl, acc, lane, wid);
  }
  #pragma unroll
  for(int r = 0; r < 4; r++){
    int i = m0 + wid*16 + (lane >> 4)*4 + r;
    if(i >= NP) continue;
    #pragma unroll
    for(int ct = 0; ct < 4; ct++){
      int c = n0 + ct*16 + (lane & 15);
      float pre = acc[ct][r] + (c < 256 ? bu[c] : br[c - 256]);
      float sg = 1.f / (1.f + __expf(-pre));
      if(c < 256){
        uOut[(size_t)i*CC + c] = sg;
      } else {
        int e = c - 256;
        float pv = prevF[(size_t)i*CC + e];
        unsigned short h, l; split_bf(sg * pv, h, l);
        prH[(size_t)i*CC + e] = h; prL[(size_t)i*CC + e] = l;
      }
    }
  }
}

// ---- GRU out ---------------------------------------------------------------
__global__ __launch_bounds__(256,4) void k_gruo(char* ws, const float* __restrict__ bo, float* __restrict__ dout, int fin){
  __shared__ unsigned short Ah[64*72], Al[64*72], Bh[64*72], Bl[64*72];
  int z = blockIdx.z, m0 = blockIdx.x*64, n0 = blockIdx.y*64;
  const unsigned short* aH0 = WSPTR(const unsigned short, O_AH)  + (size_t)z*PP*CC;
  const unsigned short* aL0 = WSPTR(const unsigned short, O_AL)  + (size_t)z*PP*CC;
  const unsigned short* aH1 = WSPTR(const unsigned short, O_PRH) + (size_t)z*PP*CC;
  const unsigned short* aL1 = WSPTR(const unsigned short, O_PRL) + (size_t)z*PP*CC;
  const unsigned short* bH  = WSPTR(const unsigned short, O_WOH) + (size_t)n0*512;
  const unsigned short* bL  = WSPTR(const unsigned short, O_WOL) + (size_t)n0*512;
  const float* uBuf = WSPTR(const float, O_U) + (size_t)z*PP*CC;
  float* sF = WSPTR(float, O_SF) + (size_t)z*PP*CC;
  unsigned short* sTh = WSPTR(unsigned short, O_STH) + (size_t)z*PP*CC;
  unsigned short* sTl = WSPTR(unsigned short, O_STL) + (size_t)z*PP*CC;
  unsigned short* sCh = WSPTR(unsigned short, O_SCH) + (size_t)z*PP*CC;
  unsigned short* sCl = WSPTR(unsigned short, O_SCL) + (size_t)z*PP*CC;
  int lane = threadIdx.x & 63, wid = threadIdx.x >> 6;
  f32x4_t acc[4] = {};
  for(int ks = 0; ks < 8; ks++){
    const unsigned short* sah = (ks < 4) ? aH0 : aH1;
    const unsigned short* sal = (ks < 4) ? aL0 : aL1;
    int koff = (ks & 3) * 64;
    __syncthreads();
    stage64(Ah, sah + (size_t)m0*256 + koff, 256);
    stage64(Al, sal + (size_t)m0*256 + koff, 256);
    stage64(Bh, bH + ks*64, 512);
    stage64(Bl, bL + ks*64, 512);
    __syncthreads();
    mfma64(Ah, Al, Bh, Bl, acc, lane, wid);
  }
  #pragma unroll
  for(int r = 0; r < 4; r++){
    int i = m0 + wid*16 + (lane >> 4)*4 + r;
    if(i >= NP) continue;
    #pragma unroll
    for(int ct = 0; ct < 4; ct++){
      int c = n0 + ct*16 + (lane & 15);
      float o = tanhf(acc[ct][r] + bo[c]);
      float uu = uBuf[(size_t)i*CC + c];
      float pv = sF[(size_t)i*CC + c];
      float h = pv*(1.f - uu) + o*uu;
      if(fin){
        dout[(size_t)z*921600 + (size_t)c*3600 + i] = h;
      } else {
        sF[(size_t)i*CC + c] = h;
        unsigned short hh, hl; split_bf(h, hh, hl);
        sTh[(size_t)i*CC + c] = hh; sTl[(size_t)i*CC + c] = hl;
        sCh[(size_t)c*PP + i] = hh; sCl[(size_t)c*PP + i] = hl;
      }
    }
  }
}

extern "C" void kernel_launch(void* const* d_in, const int* in_sizes, int n_in,
                              void* d_out, int out_size, void* d_ws, size_t ws_size,
                              hipStream_t stream){
  char* ws = (char*)d_ws;
  const float* in1   = (const float*)d_in[0];
  const float* in2   = (const float*)d_in[1];
  const float* in3   = (const float*)d_in[2];
  const float* Wlin  = (const float*)d_in[3];
  const float* Wgate = (const float*)d_in[4];
  const float* Wcf   = (const float*)d_in[5];
  const float* bcf   = (const float*)d_in[6];
  const float* Wr    = (const float*)d_in[7];
  const float* br_   = (const float*)d_in[8];
  const float* Wu    = (const float*)d_in[9];
  const float* bu_   = (const float*)d_in[10];
  const float* Wo    = (const float*)d_in[11];
  const float* bo_   = (const float*)d_in[12];

  // split-K factor limited by available workspace
  int nspl = 3;
  while(nspl > 1 && O_PO + (size_t)342*nspl*65536 > ws_size) nspl--;

  k_zero<<<dim3(2048), dim3(256), 0, stream>>>(ws);
  k_weights<<<dim3(1024), dim3(256), 0, stream>>>(ws, Wlin, Wu, Wr, Wo, Wcf);
  k_transpose<<<dim3(57, 4, 3), dim3(256), 0, stream>>>(ws, in1, in2, in3);

  for(int rd = 0; rd < 5; rd++){
    k_corr <<<dim3(57, 4, 3), dim3(256), 0, stream>>>(ws);
    k_flash<<<dim3(57, 6, nspl), dim3(256), 0, stream>>>(ws, nspl);
    k_merge<<<dim3(57, 6), dim3(256), 0, stream>>>(ws, Wgate, nspl);
    k_conv <<<dim3(60, 4, 3), dim3(256), 0, stream>>>(ws, bcf);
    k_gates<<<dim3(57, 8, 3), dim3(256), 0, stream>>>(ws, bu_, br_);
    k_gruo <<<dim3(57, 4, 3), dim3(256), 0, stream>>>(ws, bo_, (float*)d_out, rd == 4 ? 1 : 0);
  }
}

// Round 4
// 2638.210 us; speedup vs baseline: 1.9649x; 1.0376x over previous
//
#include <hip/hip_runtime.h>

typedef float f32x4_t __attribute__((ext_vector_type(4)));
typedef short bf16x8_t __attribute__((ext_vector_type(8)));

#define MFMA16(A,B,C) __builtin_amdgcn_mfma_f32_16x16x32_bf16((A),(B),(C),0,0,0)

static constexpr int CC = 256;      // channels
static constexpr int NP = 3600;     // valid tokens
static constexpr int PP = 3648;     // padded tokens (57*64)
static constexpr int CPOS = 3906;   // canvas positions (62*63, incl. slack)

static constexpr size_t SZ_F  = (size_t)PP*CC*4;
static constexpr size_t SZ_H  = (size_t)PP*CC*2;
static constexpr size_t SZ_CV = (size_t)CPOS*512*2;

static constexpr size_t O_SF   = 0;
static constexpr size_t O_STH  = O_SF   + 3*SZ_F;
static constexpr size_t O_STL  = O_STH  + 3*SZ_H;
static constexpr size_t O_SCH  = O_STL  + 3*SZ_H;
static constexpr size_t O_SCL  = O_SCH  + 3*SZ_H;
static constexpr size_t O_CORH = O_SCL  + 3*SZ_H;
static constexpr size_t O_CORL = O_CORH + 3*SZ_H;
static constexpr size_t O_CVH  = O_CORL + 3*SZ_H;
static constexpr size_t O_CVL  = O_CVH  + 3*SZ_CV;
static constexpr size_t O_WLH  = O_CVL  + 3*SZ_CV;
static constexpr size_t O_WLL  = O_WLH  + 131072;
static constexpr size_t O_WURH = O_WLL  + 131072;
static constexpr size_t O_WURL = O_WURH + 524288;
static constexpr size_t O_WOH  = O_WURL + 524288;
static constexpr size_t O_WOL  = O_WOH  + 262144;
static constexpr size_t O_WKH  = O_WOL  + 262144;
static constexpr size_t O_WKL  = O_WKH  + 2359296;
// X region: flash partials (flash->merge) OVERLAID with AH/AL/U/PRH/PRL (conv->gruo)
static constexpr size_t O_X    = O_WKL  + 2359296;
static constexpr size_t O_PML  = O_X;                 // 174*nspl*1KB
static constexpr size_t O_PO   = O_X + 2097152;       // 174*nspl*131072 B
static constexpr size_t O_AH   = O_X;
static constexpr size_t O_AL   = O_AH + 3*SZ_H;
static constexpr size_t O_U    = O_AL + 3*SZ_H;
static constexpr size_t O_PRH  = O_U  + 3*SZ_F;
static constexpr size_t O_PRL  = O_PRH + 3*SZ_H;

#define WSPTR(T, OFF) ((T*)(ws + (OFF)))

__device__ __forceinline__ unsigned short f2bf(float f){
  unsigned u = __builtin_bit_cast(unsigned, f);
  u += 0x7FFFu + ((u >> 16) & 1u);
  return (unsigned short)(u >> 16);
}
__device__ __forceinline__ float bf2f(unsigned short h){
  unsigned u = ((unsigned)h) << 16;
  return __builtin_bit_cast(float, u);
}
__device__ __forceinline__ void split_bf(float x, unsigned short &h, unsigned short &l){
  h = f2bf(x);
  l = f2bf(x - bf2f(h));
}

// async global->LDS, 16B per lane, LDS dest = wave-uniform base + lane*16
__device__ __forceinline__ void gll16(const void* g, void* l){
  __builtin_amdgcn_global_load_lds(
      (const __attribute__((address_space(1))) unsigned*)g,
      (__attribute__((address_space(3))) unsigned*)l, 16, 0, 0);
}

// ---- shared GEMM pieces for corr/conv/gru: 64x64 tile, LDS stride 72 ------
__device__ __forceinline__ void stage64(unsigned short* dst, const unsigned short* __restrict__ src, int ld){
  int t = threadIdx.x, r0 = t >> 3, c8 = (t & 7) * 8;
  #pragma unroll
  for(int h = 0; h < 2; h++){
    int r = r0 + h*32;
    *(bf16x8_t*)&dst[r*72 + c8] = *(const bf16x8_t*)&src[(size_t)r*ld + c8];
  }
}

__device__ __forceinline__ void mfma64(const unsigned short* Ah, const unsigned short* Al,
                                       const unsigned short* Bh, const unsigned short* Bl,
                                       f32x4_t acc[4], int lane, int wid){
  int kb = (lane >> 4) * 8, lr = lane & 15;
  int arow = wid*16 + lr;
  #pragma unroll
  for(int kk = 0; kk < 2; kk++){
    bf16x8_t ah = *(const bf16x8_t*)&Ah[arow*72 + kk*32 + kb];
    bf16x8_t al = *(const bf16x8_t*)&Al[arow*72 + kk*32 + kb];
    #pragma unroll
    for(int ct = 0; ct < 4; ct++){
      int brow = ct*16 + lr;
      bf16x8_t bh = *(const bf16x8_t*)&Bh[brow*72 + kk*32 + kb];
      bf16x8_t bl = *(const bf16x8_t*)&Bl[brow*72 + kk*32 + kb];
      acc[ct] = MFMA16(ah, bh, acc[ct]);
      acc[ct] = MFMA16(ah, bl, acc[ct]);
      acc[ct] = MFMA16(al, bh, acc[ct]);
    }
  }
}

// ---- zero canvases --------------------------------------------------------
__global__ void k_zero(char* ws){
  size_t n = (6*SZ_CV)/16;
  uint4* p = (uint4*)(ws + O_CVH);
  uint4 z = {0,0,0,0};
  for(size_t x = (size_t)blockIdx.x*256 + threadIdx.x; x < n; x += (size_t)gridDim.x*256) p[x] = z;
}

// ---- split weights --------------------------------------------------------
__global__ void k_weights(char* ws, const float* __restrict__ Wlin, const float* __restrict__ Wup,
                          const float* __restrict__ Wrs, const float* __restrict__ Wo,
                          const float* __restrict__ Wcf){
  const size_t N1 = 65536, N2 = N1 + 262144, N3 = N2 + 131072, N4 = N3 + 1179648;
  for(size_t x = (size_t)blockIdx.x*256 + threadIdx.x; x < N4; x += (size_t)gridDim.x*256){
    float v; unsigned short *dh, *dl; size_t off;
    if(x < N1){
      v = Wlin[x]; dh = WSPTR(unsigned short, O_WLH); dl = WSPTR(unsigned short, O_WLL); off = x;
    } else if(x < N2){
      size_t i = x - N1; int e = (int)(i >> 9), c = (int)(i & 511);
      v = (e < 256) ? Wup[(size_t)e*512 + c] : Wrs[(size_t)(e-256)*512 + c];
      dh = WSPTR(unsigned short, O_WURH); dl = WSPTR(unsigned short, O_WURL); off = i;
    } else if(x < N3){
      size_t i = x - N2; v = Wo[i];
      dh = WSPTR(unsigned short, O_WOH); dl = WSPTR(unsigned short, O_WOL); off = i;
    } else {
      size_t i = x - N3; int t = (int)(i % 9); size_t rest = i / 9;
      int ic = (int)(rest & 511), o = (int)(rest >> 9);
      v = Wcf[i]; off = (size_t)t*131072 + (size_t)o*512 + ic;
      dh = WSPTR(unsigned short, O_WKH); dl = WSPTR(unsigned short, O_WKL);
    }
    unsigned short h, l; split_bf(v, h, l);
    dh[off] = h; dl[off] = l;
  }
}

// ---- transpose inputs to token-major + make bf16 copies -------------------
__global__ __launch_bounds__(256) void k_transpose(char* ws, const float* __restrict__ in0,
                                                   const float* __restrict__ in1, const float* __restrict__ in2){
  __shared__ float tile[64*65];
  int z = blockIdx.z;
  const float* in = z == 0 ? in0 : (z == 1 ? in1 : in2);
  int p0 = blockIdx.x*64, c0 = blockIdx.y*64;
  float* sF = WSPTR(float, O_SF) + (size_t)z*PP*CC;
  unsigned short* sTh = WSPTR(unsigned short, O_STH) + (size_t)z*PP*CC;
  unsigned short* sTl = WSPTR(unsigned short, O_STL) + (size_t)z*PP*CC;
  unsigned short* sCh = WSPTR(unsigned short, O_SCH) + (size_t)z*PP*CC;
  unsigned short* sCl = WSPTR(unsigned short, O_SCL) + (size_t)z*PP*CC;
  int t = threadIdx.x, pl = t & 63, cq = t >> 6;
  #pragma unroll
  for(int rr = 0; rr < 16; rr++){
    int cl = rr*4 + cq, p = p0 + pl, c = c0 + cl;
    float v = (p < NP) ? in[(size_t)c*NP + p] : 0.f;
    tile[cl*65 + pl] = v;
    if(p < NP){
      unsigned short h, l; split_bf(v, h, l);
      sCh[(size_t)c*PP + p] = h; sCl[(size_t)c*PP + p] = l;
    }
  }
  __syncthreads();
  #pragma unroll
  for(int rr = 0; rr < 16; rr++){
    int prow = rr*4 + cq, p = p0 + prow, cl = pl;
    if(p < NP){
      float v = tile[cl*65 + prow];
      int c = c0 + cl;
      sF[(size_t)p*CC + c] = v;
      unsigned short h, l; split_bf(v, h, l);
      sTh[(size_t)p*CC + c] = h; sTl[(size_t)p*CC + c] = l;
    }
  }
}

// ---- corr = stateT @ W_lin^T ----------------------------------------------
__global__ __launch_bounds__(256,4) void k_corr(char* ws){
  __shared__ unsigned short Ah[64*72], Al[64*72], Bh[64*72], Bl[64*72];
  int z = blockIdx.z, m0 = blockIdx.x*64, n0 = blockIdx.y*64;
  const unsigned short* aH = WSPTR(const unsigned short, O_STH) + (size_t)z*PP*CC;
  const unsigned short* aL = WSPTR(const unsigned short, O_STL) + (size_t)z*PP*CC;
  const unsigned short* bH = WSPTR(const unsigned short, O_WLH);
  const unsigned short* bL = WSPTR(const unsigned short, O_WLL);
  unsigned short* cH = WSPTR(unsigned short, O_CORH) + (size_t)z*PP*CC;
  unsigned short* cL = WSPTR(unsigned short, O_CORL) + (size_t)z*PP*CC;
  int lane = threadIdx.x & 63, wid = threadIdx.x >> 6;
  f32x4_t acc[4] = {};
  for(int k0 = 0; k0 < 256; k0 += 64){
    __syncthreads();
    stage64(Ah, aH + (size_t)m0*256 + k0, 256);
    stage64(Al, aL + (size_t)m0*256 + k0, 256);
    stage64(Bh, bH + (size_t)n0*256 + k0, 256);
    stage64(Bl, bL + (size_t)n0*256 + k0, 256);
    __syncthreads();
    mfma64(Ah, Al, Bh, Bl, acc, lane, wid);
  }
  #pragma unroll
  for(int r = 0; r < 4; r++){
    int i = m0 + wid*16 + (lane >> 4)*4 + r;
    if(i >= NP) continue;
    #pragma unroll
    for(int ct = 0; ct < 4; ct++){
      int c = n0 + ct*16 + (lane & 15);
      unsigned short h, l; split_bf(acc[ct][r], h, l);
      cH[(size_t)i*CC + c] = h; cL[(size_t)i*CC + c] = l;
    }
  }
}

// ---- flash attention: 8 waves, 128 q-rows, dbuf K/V, in-reg P exchange ----
__global__ __launch_bounds__(512,2) void k_flash(char* ws, int nspl){
  __shared__ unsigned short KV[65536];   // two 64KB buffers: [h 32KB][l 32KB] each
  int n_wg = 174*nspl, lin = blockIdx.x;
  int qq = n_wg >> 3, rr = n_wg & 7, xcd = lin & 7, pos = lin >> 3;
  int wg = (xcd < rr ? xcd*(qq+1) : rr*(qq+1) + (xcd-rr)*qq) + pos;
  int qt = wg % 29, pair = (wg / 29) % 6, sp = wg / 174;
  int src = pair >> 1;
  int tgt = ((pair & 1) == 0) ? (src == 0 ? 1 : 0) : (src == 2 ? 1 : 2);
  const unsigned short* Qh = WSPTR(const unsigned short, O_CORH) + (size_t)src*PP*CC;
  const unsigned short* Ql = WSPTR(const unsigned short, O_CORL) + (size_t)src*PP*CC;
  const unsigned short* Kh = WSPTR(const unsigned short, O_STH)  + (size_t)tgt*PP*CC;
  const unsigned short* Kl = WSPTR(const unsigned short, O_STL)  + (size_t)tgt*PP*CC;
  const unsigned short* Vh = WSPTR(const unsigned short, O_SCH)  + (size_t)tgt*PP*CC;
  const unsigned short* Vl = WSPTR(const unsigned short, O_SCL)  + (size_t)tgt*PP*CC;
  int t = threadIdx.x, lane = t & 63, wid = t >> 6, lr = lane & 15, lk = lane >> 4;

  // ---- stage Q [128][256] h/l across both buffers, then read frags --------
  #pragma unroll
  for(int q = 0; q < 8; q++){
    int n = wid*8 + q;                 // 0..63 (1KB segments)
    int row = 2*n + (lane >> 5);       // 0..127
    int gch = (lane & 31) ^ (row & 7);
    size_t ga = (size_t)(qt*128 + row)*256 + gch*8;
    unsigned short* d = &KV[(row >> 6)*32768 + (n & 31)*512];
    gll16(&Qh[ga], d);
    gll16(&Ql[ga], d + 16384);
  }
  asm volatile("s_waitcnt vmcnt(0)" ::: "memory");
  __syncthreads();
  bf16x8_t qh[8], ql[8];
  {
    int qbase = (wid >> 2)*32768;
    int qrow = (wid & 3)*16 + lr;
    #pragma unroll
    for(int kq = 0; kq < 8; kq++){
      int ch = (kq*4 + lk) ^ (lr & 7);
      qh[kq] = *(const bf16x8_t*)&KV[qbase + qrow*256 + ch*8];
      ql[kq] = *(const bf16x8_t*)&KV[qbase + 16384 + qrow*256 + ch*8];
    }
  }
  __syncthreads();   // all waves done reading Q

  float m = -1e38f, lsum = 0.f;
  f32x4_t oacc[16] = {};
  int kt0 = (57*sp)/nspl, kt1 = (57*(sp+1))/nspl;
  int cur = 0;

  // prologue: stage K(kt0) -> buf0
  {
    int j0 = kt0*64;
    #pragma unroll
    for(int q = 0; q < 4; q++){
      int n = wid*4 + q;
      int row = 2*n + (lane >> 5);
      int gch = (lane & 31) ^ (row & 7);
      size_t ga = (size_t)(j0 + row)*256 + gch*8;
      unsigned short* d = &KV[n*512];
      gll16(&Kh[ga], d);
      gll16(&Kl[ga], d + 16384);
    }
  }

  for(int kt = kt0; kt < kt1; kt++){
    int j0 = kt*64;
    asm volatile("s_waitcnt vmcnt(0)" ::: "memory");
    __syncthreads();                       // K(kt) ready; prev PV reads done
    // issue K(kt+1) into other buffer (hidden under QK)
    if(kt + 1 < kt1){
      int j1 = (kt+1)*64;
      #pragma unroll
      for(int q = 0; q < 4; q++){
        int n = wid*4 + q;
        int row = 2*n + (lane >> 5);
        int gch = (lane & 31) ^ (row & 7);
        size_t ga = (size_t)(j1 + row)*256 + gch*8;
        unsigned short* d = &KV[(cur^1)*32768 + n*512];
        gll16(&Kh[ga], d);
        gll16(&Kl[ga], d + 16384);
      }
    }
    // ---- QK^T (S^T): s[ct] = K_tile . Q -> D[j_local][i=lr] ----
    const unsigned short* Kb = &KV[cur*32768];
    f32x4_t s[4] = {};
    __builtin_amdgcn_s_setprio(1);
    #pragma unroll
    for(int kq = 0; kq < 8; kq++){
      #pragma unroll
      for(int ct = 0; ct < 4; ct++){
        int arow = ct*16 + lr;
        int ch = (kq*4 + lk) ^ (lr & 7);
        bf16x8_t khv = *(const bf16x8_t*)&Kb[arow*256 + ch*8];
        bf16x8_t klv = *(const bf16x8_t*)&Kb[16384 + arow*256 + ch*8];
        s[ct] = MFMA16(khv, qh[kq], s[ct]);
        s[ct] = MFMA16(khv, ql[kq], s[ct]);
        s[ct] = MFMA16(klv, qh[kq], s[ct]);
      }
    }
    __builtin_amdgcn_s_setprio(0);
    __syncthreads();                       // QK reads complete -> buf free for V
    // issue V(kt) into current buffer (hidden under softmax)
    #pragma unroll
    for(int q = 0; q < 4; q++){
      int n = wid*4 + q;
      int c = 8*n + (lane >> 3);
      int gch = (lane & 7) ^ (c & 7);
      size_t ga = (size_t)c*PP + j0 + gch*8;
      unsigned short* d = &KV[cur*32768 + n*512];
      gll16(&Vh[ga], d);
      gll16(&Vl[ga], d + 16384);
    }
    // ---- softmax (each lane owns one query row i = lane&15) ----
    if(kt == 56){  // j >= NP: only first 16 rows of this tile valid
      #pragma unroll
      for(int ct = 1; ct < 4; ct++){ s[ct][0] = -1e30f; s[ct][1] = -1e30f; s[ct][2] = -1e30f; s[ct][3] = -1e30f; }
    }
    float pmax = s[0][0];
    #pragma unroll
    for(int ct = 0; ct < 4; ct++){
      #pragma unroll
      for(int r = 0; r < 4; r++) pmax = fmaxf(pmax, s[ct][r]);
    }
    pmax = fmaxf(pmax, __shfl_xor(pmax, 16));
    pmax = fmaxf(pmax, __shfl_xor(pmax, 32));
    bool need = pmax > m + 8.f;            // defer-max threshold
    if(__any(need)){
      float mn = need ? pmax : m;
      float sc = __expf(m - mn);
      m = mn; lsum *= sc;
      float sc4[4];
      #pragma unroll
      for(int r = 0; r < 4; r++) sc4[r] = __shfl(sc, 4*lk + r);
      #pragma unroll
      for(int c = 0; c < 16; c++){
        oacc[c][0]*=sc4[0]; oacc[c][1]*=sc4[1]; oacc[c][2]*=sc4[2]; oacc[c][3]*=sc4[3];
      }
    }
    float ps = 0.f;
    float pv[16];
    #pragma unroll
    for(int ct = 0; ct < 4; ct++){
      pv[ct*4+0] = __expf(s[ct][0]-m); pv[ct*4+1] = __expf(s[ct][1]-m);
      pv[ct*4+2] = __expf(s[ct][2]-m); pv[ct*4+3] = __expf(s[ct][3]-m);
      ps += (pv[ct*4+0]+pv[ct*4+1]) + (pv[ct*4+2]+pv[ct*4+3]);
    }
    ps += __shfl_xor(ps, 16);
    ps += __shfl_xor(ps, 32);
    lsum += ps;
    // ---- in-register P exchange -> PA frags (PV A-operand) ----
    // lane needs PA[kk][e] = P[32kk+8lk+e][lr]; verified j_got == j_want
    bf16x8_t pah[2], pal[2];
    #pragma unroll
    for(int kk = 0; kk < 2; kk++){
      #pragma unroll
      for(int ri = 0; ri < 4; ri++){
        int srcA = lr + 16*((2*lk) & 3);
        int srcB = lr + 16*((2*lk + 1) & 3);
        float a0 = __shfl(pv[(2*kk)*4 + ri],   srcA);
        float a1 = __shfl(pv[(2*kk+1)*4 + ri], srcA);
        float b0 = __shfl(pv[(2*kk)*4 + ri],   srcB);
        float b1 = __shfl(pv[(2*kk+1)*4 + ri], srcB);
        float va = (lk < 2) ? a0 : a1;   // e = ri
        float vb = (lk < 2) ? b0 : b1;   // e = 4+ri
        unsigned short h, l;
        split_bf(va, h, l); pah[kk][ri]   = (short)h; pal[kk][ri]   = (short)l;
        split_bf(vb, h, l); pah[kk][4+ri] = (short)h; pal[kk][4+ri] = (short)l;
      }
    }
    asm volatile("s_waitcnt vmcnt(0)" ::: "memory");
    __syncthreads();                       // V (and K(t+1)) ready
    // ---- PV: oacc[c16] = P^T . V -> O[i = 4lk+r][c = c16*16+lr] ----
    const unsigned short* Vb = &KV[cur*32768];
    __builtin_amdgcn_s_setprio(1);
    #pragma unroll
    for(int kk = 0; kk < 2; kk++){
      #pragma unroll
      for(int c16 = 0; c16 < 16; c16++){
        int crow = c16*16 + lr;
        int ch = (kk*4 + lk) ^ (lr & 7);
        bf16x8_t vh  = *(const bf16x8_t*)&Vb[crow*64 + ch*8];
        bf16x8_t vlo = *(const bf16x8_t*)&Vb[16384 + crow*64 + ch*8];
        oacc[c16] = MFMA16(pah[kk], vh,  oacc[c16]);
        oacc[c16] = MFMA16(pah[kk], vlo, oacc[c16]);
        oacc[c16] = MFMA16(pal[kk], vh,  oacc[c16]);
      }
    }
    __builtin_amdgcn_s_setprio(0);
    cur ^= 1;
  }
  // ---- store partials (unnormalized O w.r.t. m) ----
  int idx = (pair*29 + qt)*nspl + sp;
  float* pml = WSPTR(float, O_PML) + (size_t)idx*256;
  float* po  = WSPTR(float, O_PO)  + (size_t)idx*32768;
  if(lk == 0){ pml[wid*16 + lr] = m; pml[128 + wid*16 + lr] = lsum; }
  #pragma unroll
  for(int c16 = 0; c16 < 16; c16++){
    #pragma unroll
    for(int r = 0; r < 4; r++){
      po[(size_t)(wid*16 + 4*lk + r)*256 + c16*16 + lr] = oacc[c16][r];
    }
  }
}

// ---- merge split-K partials, gate, write canvas ----------------------------
__global__ __launch_bounds__(512) void k_merge(char* ws, const float* __restrict__ wgate, int nspl){
  int qt = blockIdx.x, pair = blockIdx.y;
  int src = pair >> 1, cho = (pair & 1)*256;
  unsigned short* cvH = WSPTR(unsigned short, O_CVH) + (size_t)src*CPOS*512 + cho;
  unsigned short* cvL = WSPTR(unsigned short, O_CVL) + (size_t)src*CPOS*512 + cho;
  int t = threadIdx.x, il = t >> 2, q4 = t & 3;
  int base = (pair*29 + qt)*nspl;
  const float* pml = WSPTR(const float, O_PML);
  const float* po  = WSPTR(const float, O_PO);
  float M = -1e38f;
  for(int s = 0; s < nspl; s++) M = fmaxf(M, pml[(size_t)(base+s)*256 + il]);
  float L = 0.f;
  float acc[64];
  #pragma unroll
  for(int k = 0; k < 64; k++) acc[k] = 0.f;
  for(int s = 0; s < nspl; s++){
    float w = __expf(pml[(size_t)(base+s)*256 + il] - M);
    L += pml[(size_t)(base+s)*256 + 128 + il]*w;
    const float* p = &po[(size_t)(base+s)*32768 + (size_t)il*256];
    #pragma unroll
    for(int k4 = 0; k4 < 16; k4++){
      f32x4_t v = *(const f32x4_t*)&p[k4*16 + q4*4];
      acc[k4*4+0] += v[0]*w; acc[k4*4+1] += v[1]*w;
      acc[k4*4+2] += v[2]*w; acc[k4*4+3] += v[3]*w;
    }
  }
  float invL = 1.f/L, g = 0.f;
  #pragma unroll
  for(int k4 = 0; k4 < 16; k4++){
    #pragma unroll
    for(int e = 0; e < 4; e++){
      acc[k4*4+e] *= invL;
      g += wgate[k4*16 + q4*4 + e] * acc[k4*4+e];
    }
  }
  g += __shfl_xor(g, 1);
  g += __shfl_xor(g, 2);
  g = 1.f/(1.f + __expf(-g));
  int i = qt*128 + il;
  if(i < NP){
    int pos = (1 + i/60)*62 + 1 + i%60;
    #pragma unroll
    for(int k4 = 0; k4 < 16; k4++){
      unsigned short h0,l0,h1,l1,h2,l2,h3,l3;
      split_bf(acc[k4*4+0]*g, h0, l0); split_bf(acc[k4*4+1]*g, h1, l1);
      split_bf(acc[k4*4+2]*g, h2, l2); split_bf(acc[k4*4+3]*g, h3, l3);
      uint2 wh = { (unsigned)h0 | ((unsigned)h1<<16), (unsigned)h2 | ((unsigned)h3<<16) };
      uint2 wl = { (unsigned)l0 | ((unsigned)l1<<16), (unsigned)l2 | ((unsigned)l3<<16) };
      *(uint2*)&cvH[(size_t)pos*512 + k4*16 + q4*4] = wh;
      *(uint2*)&cvL[(size_t)pos*512 + k4*16 + q4*4] = wl;
    }
  }
}

// ---- conv3x3 over canvas (512 -> 256), output token-major hi/lo -----------
__global__ __launch_bounds__(256,4) void k_conv(char* ws, const float* __restrict__ bcf){
  __shared__ unsigned short Ah[64*72], Al[64*72], Bh[64*72], Bl[64*72];
  int z = blockIdx.z, y = blockIdx.x, n0 = blockIdx.y*64;
  const unsigned short* cvH = WSPTR(const unsigned short, O_CVH) + (size_t)z*CPOS*512;
  const unsigned short* cvL = WSPTR(const unsigned short, O_CVL) + (size_t)z*CPOS*512;
  const unsigned short* wH = WSPTR(const unsigned short, O_WKH);
  const unsigned short* wL = WSPTR(const unsigned short, O_WKL);
  unsigned short* oH = WSPTR(unsigned short, O_AH) + (size_t)z*PP*CC;
  unsigned short* oL = WSPTR(unsigned short, O_AL) + (size_t)z*PP*CC;
  int lane = threadIdx.x & 63, wid = threadIdx.x >> 6;
  f32x4_t acc[4] = {};
  for(int t = 0; t < 9; t++){
    int posBase = (y + t/3)*62 + (t%3);
    const unsigned short* aH = cvH + (size_t)posBase*512;
    const unsigned short* aL = cvL + (size_t)posBase*512;
    const unsigned short* bH = wH + (size_t)t*131072 + (size_t)n0*512;
    const unsigned short* bL = wL + (size_t)t*131072 + (size_t)n0*512;
    for(int k0 = 0; k0 < 512; k0 += 64){
      __syncthreads();
      stage64(Ah, aH + k0, 512);
      stage64(Al, aL + k0, 512);
      stage64(Bh, bH + k0, 512);
      stage64(Bl, bL + k0, 512);
      __syncthreads();
      mfma64(Ah, Al, Bh, Bl, acc, lane, wid);
    }
  }
  #pragma unroll
  for(int r = 0; r < 4; r++){
    int x = wid*16 + (lane >> 4)*4 + r;
    if(x >= 60) continue;
    int i = y*60 + x;
    #pragma unroll
    for(int ct = 0; ct < 4; ct++){
      int c = n0 + ct*16 + (lane & 15);
      float v = acc[ct][r] + bcf[c];
      unsigned short h, l; split_bf(v, h, l);
      oH[(size_t)i*CC + c] = h; oL[(size_t)i*CC + c] = l;
    }
  }
}

// ---- GRU gates -------------------------------------------------------------
__global__ __launch_bounds__(256,4) void k_gates(char* ws, const float* __restrict__ bu, const float* __restrict__ br){
  __shared__ unsigned short Ah[64*72], Al[64*72], Bh[64*72], Bl[64*72];
  int z = blockIdx.z, m0 = blockIdx.x*64, n0 = blockIdx.y*64;
  const unsigned short* aH0 = WSPTR(const unsigned short, O_AH)  + (size_t)z*PP*CC;
  const unsigned short* aL0 = WSPTR(const unsigned short, O_AL)  + (size_t)z*PP*CC;
  const unsigned short* aH1 = WSPTR(const unsigned short, O_STH) + (size_t)z*PP*CC;
  const unsigned short* aL1 = WSPTR(const unsigned short, O_STL) + (size_t)z*PP*CC;
  const unsigned short* bH  = WSPTR(const unsigned short, O_WURH) + (size_t)n0*512;
  const unsigned short* bL  = WSPTR(const unsigned short, O_WURL) + (size_t)n0*512;
  const float* prevF = WSPTR(const float, O_SF) + (size_t)z*PP*CC;
  float* uOut = WSPTR(float, O_U) + (size_t)z*PP*CC;
  unsigned short* prH = WSPTR(unsigned short, O_PRH) + (size_t)z*PP*CC;
  unsigned short* prL = WSPTR(unsigned short, O_PRL) + (size_t)z*PP*CC;
  int lane = threadIdx.x & 63, wid = threadIdx.x >> 6;
  f32x4_t acc[4] = {};
  for(int ks = 0; ks < 8; ks++){
    const unsigned short* sah = (ks < 4) ? aH0 : aH1;
    const unsigned short* sal = (ks < 4) ? aL0 : aL1;
    int koff = (ks & 3) * 64;
    __syncthreads();
    stage64(Ah, sah + (size_t)m0*256 + koff, 256);
    stage64(Al, sal + (size_t)m0*256 + koff, 256);
    stage64(Bh, bH + ks*64, 512);
    stage64(Bl, bL + ks*64, 512);
    __syncthreads();
    mfma64(Ah, Al, Bh, Bl, acc, lane, wid);
  }
  #pragma unroll
  for(int r = 0; r < 4; r++){
    int i = m0 + wid*16 + (lane >> 4)*4 + r;
    if(i >= NP) continue;
    #pragma unroll
    for(int ct = 0; ct < 4; ct++){
      int c = n0 + ct*16 + (lane & 15);
      float pre = acc[ct][r] + (c < 256 ? bu[c] : br[c - 256]);
      float sg = 1.f / (1.f + __expf(-pre));
      if(c < 256){
        uOut[(size_t)i*CC + c] = sg;
      } else {
        int e = c - 256;
        float pv = prevF[(size_t)i*CC + e];
        unsigned short h, l; split_bf(sg * pv, h, l);
        prH[(size_t)i*CC + e] = h; prL[(size_t)i*CC + e] = l;
      }
    }
  }
}

// ---- GRU out ---------------------------------------------------------------
__global__ __launch_bounds__(256,4) void k_gruo(char* ws, const float* __restrict__ bo, float* __restrict__ dout, int fin){
  __shared__ unsigned short Ah[64*72], Al[64*72], Bh[64*72], Bl[64*72];
  int z = blockIdx.z, m0 = blockIdx.x*64, n0 = blockIdx.y*64;
  const unsigned short* aH0 = WSPTR(const unsigned short, O_AH)  + (size_t)z*PP*CC;
  const unsigned short* aL0 = WSPTR(const unsigned short, O_AL)  + (size_t)z*PP*CC;
  const unsigned short* aH1 = WSPTR(const unsigned short, O_PRH) + (size_t)z*PP*CC;
  const unsigned short* aL1 = WSPTR(const unsigned short, O_PRL) + (size_t)z*PP*CC;
  const unsigned short* bH  = WSPTR(const unsigned short, O_WOH) + (size_t)n0*512;
  const unsigned short* bL  = WSPTR(const unsigned short, O_WOL) + (size_t)n0*512;
  const float* uBuf = WSPTR(const float, O_U) + (size_t)z*PP*CC;
  float* sF = WSPTR(float, O_SF) + (size_t)z*PP*CC;
  unsigned short* sTh = WSPTR(unsigned short, O_STH) + (size_t)z*PP*CC;
  unsigned short* sTl = WSPTR(unsigned short, O_STL) + (size_t)z*PP*CC;
  unsigned short* sCh = WSPTR(unsigned short, O_SCH) + (size_t)z*PP*CC;
  unsigned short* sCl = WSPTR(unsigned short, O_SCL) + (size_t)z*PP*CC;
  int lane = threadIdx.x & 63, wid = threadIdx.x >> 6;
  f32x4_t acc[4] = {};
  for(int ks = 0; ks < 8; ks++){
    const unsigned short* sah = (ks < 4) ? aH0 : aH1;
    const unsigned short* sal = (ks < 4) ? aL0 : aL1;
    int koff = (ks & 3) * 64;
    __syncthreads();
    stage64(Ah, sah + (size_t)m0*256 + koff, 256);
    stage64(Al, sal + (size_t)m0*256 + koff, 256);
    stage64(Bh, bH + ks*64, 512);
    stage64(Bl, bL + ks*64, 512);
    __syncthreads();
    mfma64(Ah, Al, Bh, Bl, acc, lane, wid);
  }
  #pragma unroll
  for(int r = 0; r < 4; r++){
    int i = m0 + wid*16 + (lane >> 4)*4 + r;
    if(i >= NP) continue;
    #pragma unroll
    for(int ct = 0; ct < 4; ct++){
      int c = n0 + ct*16 + (lane & 15);
      float o = tanhf(acc[ct][r] + bo[c]);
      float uu = uBuf[(size_t)i*CC + c];
      float pv = sF[(size_t)i*CC + c];
      float h = pv*(1.f - uu) + o*uu;
      if(fin){
        dout[(size_t)z*921600 + (size_t)c*3600 + i] = h;
      } else {
        sF[(size_t)i*CC + c] = h;
        unsigned short hh, hl; split_bf(h, hh, hl);
        sTh[(size_t)i*CC + c] = hh; sTl[(size_t)i*CC + c] = hl;
        sCh[(size_t)c*PP + i] = hh; sCl[(size_t)c*PP + i] = hl;
      }
    }
  }
}

extern "C" void kernel_launch(void* const* d_in, const int* in_sizes, int n_in,
                              void* d_out, int out_size, void* d_ws, size_t ws_size,
                              hipStream_t stream){
  char* ws = (char*)d_ws;
  const float* in1   = (const float*)d_in[0];
  const float* in2   = (const float*)d_in[1];
  const float* in3   = (const float*)d_in[2];
  const float* Wlin  = (const float*)d_in[3];
  const float* Wgate = (const float*)d_in[4];
  const float* Wcf   = (const float*)d_in[5];
  const float* bcf   = (const float*)d_in[6];
  const float* Wr    = (const float*)d_in[7];
  const float* br_   = (const float*)d_in[8];
  const float* Wu    = (const float*)d_in[9];
  const float* bu_   = (const float*)d_in[10];
  const float* Wo    = (const float*)d_in[11];
  const float* bo_   = (const float*)d_in[12];

  // split-K factor limited by available workspace
  int nspl = 4;
  while(nspl > 1 && O_PO + (size_t)174*nspl*131072 > ws_size) nspl--;

  k_zero<<<dim3(2048), dim3(256), 0, stream>>>(ws);
  k_weights<<<dim3(1024), dim3(256), 0, stream>>>(ws, Wlin, Wu, Wr, Wo, Wcf);
  k_transpose<<<dim3(57, 4, 3), dim3(256), 0, stream>>>(ws, in1, in2, in3);

  for(int rd = 0; rd < 5; rd++){
    k_corr <<<dim3(57, 4, 3), dim3(256), 0, stream>>>(ws);
    k_flash<<<dim3(174*nspl), dim3(512), 0, stream>>>(ws, nspl);
    k_merge<<<dim3(29, 6), dim3(512), 0, stream>>>(ws, Wgate, nspl);
    k_conv <<<dim3(60, 4, 3), dim3(256), 0, stream>>>(ws, bcf);
    k_gates<<<dim3(57, 8, 3), dim3(256), 0, stream>>>(ws, bu_, br_);
    k_gruo <<<dim3(57, 4, 3), dim3(256), 0, stream>>>(ws, bo_, (float*)d_out, rd == 4 ? 1 : 0);
  }
}

// Round 5
// 2613.417 us; speedup vs baseline: 1.9836x; 1.0095x over previous
//
#include <hip/hip_runtime.h>

typedef float f32x4_t __attribute__((ext_vector_type(4)));
typedef short bf16x8_t __attribute__((ext_vector_type(8)));

#define MFMA16(A,B,C) __builtin_amdgcn_mfma_f32_16x16x32_bf16((A),(B),(C),0,0,0)

static constexpr int CC = 256;      // channels
static constexpr int NP = 3600;     // valid tokens
static constexpr int PP = 3648;     // padded tokens (57*64)
static constexpr int CPOS = 3906;   // canvas positions (62*63, incl. slack)

static constexpr size_t SZ_F  = (size_t)PP*CC*4;
static constexpr size_t SZ_H  = (size_t)PP*CC*2;
static constexpr size_t SZ_CV = (size_t)CPOS*512*2;

static constexpr size_t O_SF   = 0;
static constexpr size_t O_STH  = O_SF   + 3*SZ_F;
static constexpr size_t O_STL  = O_STH  + 3*SZ_H;
static constexpr size_t O_SCH  = O_STL  + 3*SZ_H;
static constexpr size_t O_SCL  = O_SCH  + 3*SZ_H;
static constexpr size_t O_CORH = O_SCL  + 3*SZ_H;
static constexpr size_t O_CORL = O_CORH + 3*SZ_H;
static constexpr size_t O_CVH  = O_CORL + 3*SZ_H;
static constexpr size_t O_CVL  = O_CVH  + 3*SZ_CV;
static constexpr size_t O_WLH  = O_CVL  + 3*SZ_CV;
static constexpr size_t O_WLL  = O_WLH  + 131072;
static constexpr size_t O_WURH = O_WLL  + 131072;
static constexpr size_t O_WURL = O_WURH + 524288;
static constexpr size_t O_WOH  = O_WURL + 524288;
static constexpr size_t O_WOL  = O_WOH  + 262144;
static constexpr size_t O_WKH  = O_WOL  + 262144;
static constexpr size_t O_WKL  = O_WKH  + 2359296;
// X region: flash partials (flash->merge) OVERLAID with AH/AL/U/PRH/PRL (conv->gruo)
static constexpr size_t O_X    = O_WKL  + 2359296;
static constexpr size_t O_PML  = O_X;                 // 342*nspl*512 B
static constexpr size_t O_PO   = O_X + 2097152;       // 342*nspl*65536 B
static constexpr size_t O_AH   = O_X;
static constexpr size_t O_AL   = O_AH + 3*SZ_H;
static constexpr size_t O_U    = O_AL + 3*SZ_H;
static constexpr size_t O_PRH  = O_U  + 3*SZ_F;
static constexpr size_t O_PRL  = O_PRH + 3*SZ_H;

#define WSPTR(T, OFF) ((T*)(ws + (OFF)))

__device__ __forceinline__ unsigned short f2bf(float f){
  unsigned u = __builtin_bit_cast(unsigned, f);
  u += 0x7FFFu + ((u >> 16) & 1u);
  return (unsigned short)(u >> 16);
}
__device__ __forceinline__ float bf2f(unsigned short h){
  unsigned u = ((unsigned)h) << 16;
  return __builtin_bit_cast(float, u);
}
__device__ __forceinline__ void split_bf(float x, unsigned short &h, unsigned short &l){
  h = f2bf(x);
  l = f2bf(x - bf2f(h));
}

// async global->LDS, 16B per lane, LDS dest = wave-uniform base + lane*16
__device__ __forceinline__ void gll16(const void* g, void* l){
  __builtin_amdgcn_global_load_lds(
      (const __attribute__((address_space(1))) unsigned*)g,
      (__attribute__((address_space(3))) unsigned*)l, 16, 0, 0);
}

// ---- shared GEMM pieces for corr/conv/gru: 64x64 tile, LDS stride 72 ------
__device__ __forceinline__ void stage64(unsigned short* dst, const unsigned short* __restrict__ src, int ld){
  int t = threadIdx.x, r0 = t >> 3, c8 = (t & 7) * 8;
  #pragma unroll
  for(int h = 0; h < 2; h++){
    int r = r0 + h*32;
    *(bf16x8_t*)&dst[r*72 + c8] = *(const bf16x8_t*)&src[(size_t)r*ld + c8];
  }
}

__device__ __forceinline__ void mfma64(const unsigned short* Ah, const unsigned short* Al,
                                       const unsigned short* Bh, const unsigned short* Bl,
                                       f32x4_t acc[4], int lane, int wid){
  int kb = (lane >> 4) * 8, lr = lane & 15;
  int arow = wid*16 + lr;
  #pragma unroll
  for(int kk = 0; kk < 2; kk++){
    bf16x8_t ah = *(const bf16x8_t*)&Ah[arow*72 + kk*32 + kb];
    bf16x8_t al = *(const bf16x8_t*)&Al[arow*72 + kk*32 + kb];
    #pragma unroll
    for(int ct = 0; ct < 4; ct++){
      int brow = ct*16 + lr;
      bf16x8_t bh = *(const bf16x8_t*)&Bh[brow*72 + kk*32 + kb];
      bf16x8_t bl = *(const bf16x8_t*)&Bl[brow*72 + kk*32 + kb];
      acc[ct] = MFMA16(ah, bh, acc[ct]);
      acc[ct] = MFMA16(ah, bl, acc[ct]);
      acc[ct] = MFMA16(al, bh, acc[ct]);
    }
  }
}

// ---- zero canvases --------------------------------------------------------
__global__ void k_zero(char* ws){
  size_t n = (6*SZ_CV)/16;
  uint4* p = (uint4*)(ws + O_CVH);
  uint4 z = {0,0,0,0};
  for(size_t x = (size_t)blockIdx.x*256 + threadIdx.x; x < n; x += (size_t)gridDim.x*256) p[x] = z;
}

// ---- split weights --------------------------------------------------------
__global__ void k_weights(char* ws, const float* __restrict__ Wlin, const float* __restrict__ Wup,
                          const float* __restrict__ Wrs, const float* __restrict__ Wo,
                          const float* __restrict__ Wcf){
  const size_t N1 = 65536, N2 = N1 + 262144, N3 = N2 + 131072, N4 = N3 + 1179648;
  for(size_t x = (size_t)blockIdx.x*256 + threadIdx.x; x < N4; x += (size_t)gridDim.x*256){
    float v; unsigned short *dh, *dl; size_t off;
    if(x < N1){
      v = Wlin[x]; dh = WSPTR(unsigned short, O_WLH); dl = WSPTR(unsigned short, O_WLL); off = x;
    } else if(x < N2){
      size_t i = x - N1; int e = (int)(i >> 9), c = (int)(i & 511);
      v = (e < 256) ? Wup[(size_t)e*512 + c] : Wrs[(size_t)(e-256)*512 + c];
      dh = WSPTR(unsigned short, O_WURH); dl = WSPTR(unsigned short, O_WURL); off = i;
    } else if(x < N3){
      size_t i = x - N2; v = Wo[i];
      dh = WSPTR(unsigned short, O_WOH); dl = WSPTR(unsigned short, O_WOL); off = i;
    } else {
      size_t i = x - N3; int t = (int)(i % 9); size_t rest = i / 9;
      int ic = (int)(rest & 511), o = (int)(rest >> 9);
      v = Wcf[i]; off = (size_t)t*131072 + (size_t)o*512 + ic;
      dh = WSPTR(unsigned short, O_WKH); dl = WSPTR(unsigned short, O_WKL);
    }
    unsigned short h, l; split_bf(v, h, l);
    dh[off] = h; dl[off] = l;
  }
}

// ---- transpose inputs to token-major + make bf16 copies -------------------
__global__ __launch_bounds__(256) void k_transpose(char* ws, const float* __restrict__ in0,
                                                   const float* __restrict__ in1, const float* __restrict__ in2){
  __shared__ float tile[64*65];
  int z = blockIdx.z;
  const float* in = z == 0 ? in0 : (z == 1 ? in1 : in2);
  int p0 = blockIdx.x*64, c0 = blockIdx.y*64;
  float* sF = WSPTR(float, O_SF) + (size_t)z*PP*CC;
  unsigned short* sTh = WSPTR(unsigned short, O_STH) + (size_t)z*PP*CC;
  unsigned short* sTl = WSPTR(unsigned short, O_STL) + (size_t)z*PP*CC;
  unsigned short* sCh = WSPTR(unsigned short, O_SCH) + (size_t)z*PP*CC;
  unsigned short* sCl = WSPTR(unsigned short, O_SCL) + (size_t)z*PP*CC;
  int t = threadIdx.x, pl = t & 63, cq = t >> 6;
  #pragma unroll
  for(int rr = 0; rr < 16; rr++){
    int cl = rr*4 + cq, p = p0 + pl, c = c0 + cl;
    float v = (p < NP) ? in[(size_t)c*NP + p] : 0.f;
    tile[cl*65 + pl] = v;
    if(p < NP){
      unsigned short h, l; split_bf(v, h, l);
      sCh[(size_t)c*PP + p] = h; sCl[(size_t)c*PP + p] = l;
    }
  }
  __syncthreads();
  #pragma unroll
  for(int rr = 0; rr < 16; rr++){
    int prow = rr*4 + cq, p = p0 + prow, cl = pl;
    if(p < NP){
      float v = tile[cl*65 + prow];
      int c = c0 + cl;
      sF[(size_t)p*CC + c] = v;
      unsigned short h, l; split_bf(v, h, l);
      sTh[(size_t)p*CC + c] = h; sTl[(size_t)p*CC + c] = l;
    }
  }
}

// ---- corr = stateT @ W_lin^T ----------------------------------------------
__global__ __launch_bounds__(256,4) void k_corr(char* ws){
  __shared__ unsigned short Ah[64*72], Al[64*72], Bh[64*72], Bl[64*72];
  int z = blockIdx.z, m0 = blockIdx.x*64, n0 = blockIdx.y*64;
  const unsigned short* aH = WSPTR(const unsigned short, O_STH) + (size_t)z*PP*CC;
  const unsigned short* aL = WSPTR(const unsigned short, O_STL) + (size_t)z*PP*CC;
  const unsigned short* bH = WSPTR(const unsigned short, O_WLH);
  const unsigned short* bL = WSPTR(const unsigned short, O_WLL);
  unsigned short* cH = WSPTR(unsigned short, O_CORH) + (size_t)z*PP*CC;
  unsigned short* cL = WSPTR(unsigned short, O_CORL) + (size_t)z*PP*CC;
  int lane = threadIdx.x & 63, wid = threadIdx.x >> 6;
  f32x4_t acc[4] = {};
  for(int k0 = 0; k0 < 256; k0 += 64){
    __syncthreads();
    stage64(Ah, aH + (size_t)m0*256 + k0, 256);
    stage64(Al, aL + (size_t)m0*256 + k0, 256);
    stage64(Bh, bH + (size_t)n0*256 + k0, 256);
    stage64(Bl, bL + (size_t)n0*256 + k0, 256);
    __syncthreads();
    mfma64(Ah, Al, Bh, Bl, acc, lane, wid);
  }
  #pragma unroll
  for(int r = 0; r < 4; r++){
    int i = m0 + wid*16 + (lane >> 4)*4 + r;
    if(i >= NP) continue;
    #pragma unroll
    for(int ct = 0; ct < 4; ct++){
      int c = n0 + ct*16 + (lane & 15);
      unsigned short h, l; split_bf(acc[ct][r], h, l);
      cH[(size_t)i*CC + c] = h; cL[(size_t)i*CC + c] = l;
    }
  }
}

// ---- flash attention: 4 waves, 64 q-rows, single 64KB buffer (2 blk/CU) ---
__global__ __launch_bounds__(256,2) void k_flash(char* ws, int nspl){
  __shared__ unsigned short KV[32768];   // 64KB: [hi 32KB][lo 32KB]
  int n_wg = 342*nspl, lin = blockIdx.x;
  int qq = n_wg >> 3, rr2 = n_wg & 7, xcd = lin & 7, pos = lin >> 3;
  int wg = (xcd < rr2 ? xcd*(qq+1) : rr2*(qq+1) + (xcd-rr2)*qq) + pos;
  int qt = wg % 57, sp = (wg/57) % nspl, pair = wg/(57*nspl);
  int src = pair >> 1;
  int tgt = ((pair & 1) == 0) ? (src == 0 ? 1 : 0) : (src == 2 ? 1 : 2);
  const unsigned short* Qh = WSPTR(const unsigned short, O_CORH) + (size_t)src*PP*CC;
  const unsigned short* Ql = WSPTR(const unsigned short, O_CORL) + (size_t)src*PP*CC;
  const unsigned short* Kh = WSPTR(const unsigned short, O_STH)  + (size_t)tgt*PP*CC;
  const unsigned short* Kl = WSPTR(const unsigned short, O_STL)  + (size_t)tgt*PP*CC;
  const unsigned short* Vh = WSPTR(const unsigned short, O_SCH)  + (size_t)tgt*PP*CC;
  const unsigned short* Vl = WSPTR(const unsigned short, O_SCL)  + (size_t)tgt*PP*CC;
  int t = threadIdx.x, lane = t & 63, wid = t >> 6, lr = lane & 15, lk = lane >> 4;

  // ---- stage Q [64][256] h+l, pre-swizzled source, then read frags --------
  #pragma unroll
  for(int q = 0; q < 8; q++){
    int n = wid*8 + q;                 // 0..31 (1KB segments)
    int row = 2*n + (lane >> 5);
    int gch = (lane & 31) ^ (row & 7);
    size_t ga = (size_t)(qt*64 + row)*256 + gch*8;
    gll16(&Qh[ga], &KV[n*512]);
    gll16(&Ql[ga], &KV[16384 + n*512]);
  }
  asm volatile("s_waitcnt vmcnt(0)" ::: "memory");
  __syncthreads();
  bf16x8_t qh[8], ql[8];
  {
    int qrow = wid*16 + lr;
    #pragma unroll
    for(int kq = 0; kq < 8; kq++){
      int ch = (kq*4 + lk) ^ (lr & 7);
      qh[kq] = *(const bf16x8_t*)&KV[qrow*256 + ch*8];
      ql[kq] = *(const bf16x8_t*)&KV[16384 + qrow*256 + ch*8];
    }
  }
  __syncthreads();   // all waves done reading Q

  float m = -1e38f, lsum = 0.f;
  f32x4_t oacc[16] = {};
  int kt0 = (57*sp)/nspl, kt1 = (57*(sp+1))/nspl;

  // prologue: issue K(kt0)
  #pragma unroll
  for(int q = 0; q < 8; q++){
    int n = wid*8 + q;
    int row = 2*n + (lane >> 5);
    int gch = (lane & 31) ^ (row & 7);
    size_t ga = (size_t)(kt0*64 + row)*256 + gch*8;
    gll16(&Kh[ga], &KV[n*512]);
    gll16(&Kl[ga], &KV[16384 + n*512]);
  }

  for(int kt = kt0; kt < kt1; kt++){
    int j0 = kt*64;
    asm volatile("s_waitcnt vmcnt(0)" ::: "memory");
    __syncthreads();                       // K(kt) in LDS
    // ---- QK^T (S^T): s[ct] = K_tile . Q -> D[j_local][i=lr] ----
    f32x4_t s[4] = {};
    __builtin_amdgcn_s_setprio(1);
    #pragma unroll
    for(int kq = 0; kq < 8; kq++){
      #pragma unroll
      for(int ct = 0; ct < 4; ct++){
        int arow = ct*16 + lr;
        int ch = (kq*4 + lk) ^ (lr & 7);
        bf16x8_t khv = *(const bf16x8_t*)&KV[arow*256 + ch*8];
        bf16x8_t klv = *(const bf16x8_t*)&KV[16384 + arow*256 + ch*8];
        s[ct] = MFMA16(khv, qh[kq], s[ct]);
        s[ct] = MFMA16(khv, ql[kq], s[ct]);
        s[ct] = MFMA16(klv, qh[kq], s[ct]);
      }
    }
    __builtin_amdgcn_s_setprio(0);
    __syncthreads();                       // QK reads complete -> buffer free
    // issue V(kt) [256 c][64 j] h+l (flies during softmax)
    #pragma unroll
    for(int q = 0; q < 8; q++){
      int n = wid*8 + q;
      int c = 8*n + (lane >> 3);
      int gch = (lane & 7) ^ (c & 7);
      size_t ga = (size_t)c*PP + j0 + gch*8;
      gll16(&Vh[ga], &KV[n*512]);
      gll16(&Vl[ga], &KV[16384 + n*512]);
    }
    // ---- softmax (each lane owns one query row i = lane&15) ----
    if(kt == 56){  // j >= NP: only first 16 rows of this tile valid
      #pragma unroll
      for(int ct = 1; ct < 4; ct++){ s[ct][0] = -1e30f; s[ct][1] = -1e30f; s[ct][2] = -1e30f; s[ct][3] = -1e30f; }
    }
    float pmax = s[0][0];
    #pragma unroll
    for(int ct = 0; ct < 4; ct++){
      #pragma unroll
      for(int r = 0; r < 4; r++) pmax = fmaxf(pmax, s[ct][r]);
    }
    pmax = fmaxf(pmax, __shfl_xor(pmax, 16));
    pmax = fmaxf(pmax, __shfl_xor(pmax, 32));
    bool need = pmax > m + 8.f;            // defer-max threshold
    if(__any(need)){
      float mn = need ? pmax : m;
      float sc = __expf(m - mn);
      m = mn; lsum *= sc;
      float sc4[4];
      #pragma unroll
      for(int r = 0; r < 4; r++) sc4[r] = __shfl(sc, 4*lk + r);
      #pragma unroll
      for(int c = 0; c < 16; c++){
        oacc[c][0]*=sc4[0]; oacc[c][1]*=sc4[1]; oacc[c][2]*=sc4[2]; oacc[c][3]*=sc4[3];
      }
    }
    float ps = 0.f;
    float pv[16];
    #pragma unroll
    for(int ct = 0; ct < 4; ct++){
      pv[ct*4+0] = __expf(s[ct][0]-m); pv[ct*4+1] = __expf(s[ct][1]-m);
      pv[ct*4+2] = __expf(s[ct][2]-m); pv[ct*4+3] = __expf(s[ct][3]-m);
      ps += (pv[ct*4+0]+pv[ct*4+1]) + (pv[ct*4+2]+pv[ct*4+3]);
    }
    ps += __shfl_xor(ps, 16);
    ps += __shfl_xor(ps, 32);
    lsum += ps;
    // ---- in-register P exchange (bf16-hi only, packed pairs) ----
    // pa[kk][ri]   = bf16(P[32kk+8lk+ri][lr]),  pa[kk][4+ri] = bf16(P[32kk+8lk+4+ri][lr])
    unsigned pkd[8];
    #pragma unroll
    for(int a = 0; a < 2; a++){
      #pragma unroll
      for(int ri = 0; ri < 4; ri++){
        asm("v_cvt_pk_bf16_f32 %0, %1, %2" : "=v"(pkd[a*4+ri]) : "v"(pv[(2*a)*4+ri]), "v"(pv[(2*a+1)*4+ri]));
      }
    }
    int srcA = lr + 16*((2*lk) & 3);
    int srcB = lr + 16*((2*lk + 1) & 3);
    bf16x8_t pah[2];
    #pragma unroll
    for(int kk = 0; kk < 2; kk++){
      #pragma unroll
      for(int ri = 0; ri < 4; ri++){
        unsigned ua = (unsigned)__shfl((int)pkd[kk*4+ri], srcA);
        unsigned ub = (unsigned)__shfl((int)pkd[kk*4+ri], srcB);
        unsigned va = (lk < 2) ? (ua & 0xffffu) : (ua >> 16);
        unsigned vb = (lk < 2) ? (ub & 0xffffu) : (ub >> 16);
        pah[kk][ri]   = (short)va;
        pah[kk][4+ri] = (short)vb;
      }
    }
    asm volatile("s_waitcnt vmcnt(0)" ::: "memory");
    __syncthreads();                       // V ready
    // ---- PV (2-product): oacc[c16] += Ph . V -> O[i=4lk+r][c=c16*16+lr] ----
    __builtin_amdgcn_s_setprio(1);
    #pragma unroll
    for(int kk = 0; kk < 2; kk++){
      #pragma unroll
      for(int c16 = 0; c16 < 16; c16++){
        int crow = c16*16 + lr;
        int ch = (kk*4 + lk) ^ (lr & 7);
        bf16x8_t vh  = *(const bf16x8_t*)&KV[crow*64 + ch*8];
        bf16x8_t vlo = *(const bf16x8_t*)&KV[16384 + crow*64 + ch*8];
        oacc[c16] = MFMA16(pah[kk], vh,  oacc[c16]);
        oacc[c16] = MFMA16(pah[kk], vlo, oacc[c16]);
      }
    }
    __builtin_amdgcn_s_setprio(0);
    __syncthreads();                       // PV reads done -> buffer free
    // issue K(kt+1)
    if(kt + 1 < kt1){
      int j1 = (kt+1)*64;
      #pragma unroll
      for(int q = 0; q < 8; q++){
        int n = wid*8 + q;
        int row = 2*n + (lane >> 5);
        int gch = (lane & 31) ^ (row & 7);
        size_t ga = (size_t)(j1 + row)*256 + gch*8;
        gll16(&Kh[ga], &KV[n*512]);
        gll16(&Kl[ga], &KV[16384 + n*512]);
      }
    }
  }
  // ---- store partials (unnormalized O w.r.t. m) ----
  int idx = (pair*57 + qt)*nspl + sp;
  float* pml = WSPTR(float, O_PML) + (size_t)idx*128;
  float* po  = WSPTR(float, O_PO)  + (size_t)idx*16384;
  if(lk == 0){ pml[wid*16 + lr] = m; pml[64 + wid*16 + lr] = lsum; }
  #pragma unroll
  for(int c16 = 0; c16 < 16; c16++){
    #pragma unroll
    for(int r = 0; r < 4; r++){
      po[(size_t)(wid*16 + 4*lk + r)*256 + c16*16 + lr] = oacc[c16][r];
    }
  }
}

// ---- merge split-K partials, gate, write canvas ----------------------------
__global__ __launch_bounds__(256) void k_merge(char* ws, const float* __restrict__ wgate, int nspl){
  int qt = blockIdx.x, pair = blockIdx.y;
  int src = pair >> 1, cho = (pair & 1)*256;
  unsigned short* cvH = WSPTR(unsigned short, O_CVH) + (size_t)src*CPOS*512 + cho;
  unsigned short* cvL = WSPTR(unsigned short, O_CVL) + (size_t)src*CPOS*512 + cho;
  int t = threadIdx.x, il = t >> 2, q4 = t & 3;
  int base = (pair*57 + qt)*nspl;
  const float* pml = WSPTR(const float, O_PML);
  const float* po  = WSPTR(const float, O_PO);
  float M = -1e38f;
  for(int s = 0; s < nspl; s++) M = fmaxf(M, pml[(size_t)(base+s)*128 + il]);
  float L = 0.f;
  float acc[64];
  #pragma unroll
  for(int k = 0; k < 64; k++) acc[k] = 0.f;
  for(int s = 0; s < nspl; s++){
    float w = __expf(pml[(size_t)(base+s)*128 + il] - M);
    L += pml[(size_t)(base+s)*128 + 64 + il]*w;
    const float* p = &po[(size_t)(base+s)*16384 + (size_t)il*256];
    #pragma unroll
    for(int k4 = 0; k4 < 16; k4++){
      f32x4_t v = *(const f32x4_t*)&p[k4*16 + q4*4];
      acc[k4*4+0] += v[0]*w; acc[k4*4+1] += v[1]*w;
      acc[k4*4+2] += v[2]*w; acc[k4*4+3] += v[3]*w;
    }
  }
  float invL = 1.f/L, g = 0.f;
  #pragma unroll
  for(int k4 = 0; k4 < 16; k4++){
    #pragma unroll
    for(int e = 0; e < 4; e++){
      acc[k4*4+e] *= invL;
      g += wgate[k4*16 + q4*4 + e] * acc[k4*4+e];
    }
  }
  g += __shfl_xor(g, 1);
  g += __shfl_xor(g, 2);
  g = 1.f/(1.f + __expf(-g));
  int i = qt*64 + il;
  if(i < NP){
    int pos = (1 + i/60)*62 + 1 + i%60;
    #pragma unroll
    for(int k4 = 0; k4 < 16; k4++){
      unsigned short h0,l0,h1,l1,h2,l2,h3,l3;
      split_bf(acc[k4*4+0]*g, h0, l0); split_bf(acc[k4*4+1]*g, h1, l1);
      split_bf(acc[k4*4+2]*g, h2, l2); split_bf(acc[k4*4+3]*g, h3, l3);
      uint2 wh = { (unsigned)h0 | ((unsigned)h1<<16), (unsigned)h2 | ((unsigned)h3<<16) };
      uint2 wl = { (unsigned)l0 | ((unsigned)l1<<16), (unsigned)l2 | ((unsigned)l3<<16) };
      *(uint2*)&cvH[(size_t)pos*512 + k4*16 + q4*4] = wh;
      *(uint2*)&cvL[(size_t)pos*512 + k4*16 + q4*4] = wl;
    }
  }
}

// ---- conv3x3 over canvas (512 -> 256), XCD-chunked for weight L2 reuse ----
__global__ __launch_bounds__(256,4) void k_conv(char* ws, const float* __restrict__ bcf){
  __shared__ unsigned short Ah[64*72], Al[64*72], Bh[64*72], Bl[64*72];
  // 720 blocks; order idx = (z*4+n)*60 + y, chunked across 8 XCDs
  int lin = blockIdx.x;
  int wg = (lin & 7)*90 + (lin >> 3);
  int y = wg % 60, zn = wg / 60;
  int n0 = (zn & 3)*64, z = zn >> 2;
  const unsigned short* cvH = WSPTR(const unsigned short, O_CVH) + (size_t)z*CPOS*512;
  const unsigned short* cvL = WSPTR(const unsigned short, O_CVL) + (size_t)z*CPOS*512;
  const unsigned short* wH = WSPTR(const unsigned short, O_WKH);
  const unsigned short* wL = WSPTR(const unsigned short, O_WKL);
  unsigned short* oH = WSPTR(unsigned short, O_AH) + (size_t)z*PP*CC;
  unsigned short* oL = WSPTR(unsigned short, O_AL) + (size_t)z*PP*CC;
  int lane = threadIdx.x & 63, wid = threadIdx.x >> 6;
  f32x4_t acc[4] = {};
  for(int t = 0; t < 9; t++){
    int posBase = (y + t/3)*62 + (t%3);
    const unsigned short* aH = cvH + (size_t)posBase*512;
    const unsigned short* aL = cvL + (size_t)posBase*512;
    const unsigned short* bH = wH + (size_t)t*131072 + (size_t)n0*512;
    const unsigned short* bL = wL + (size_t)t*131072 + (size_t)n0*512;
    for(int k0 = 0; k0 < 512; k0 += 64){
      __syncthreads();
      stage64(Ah, aH + k0, 512);
      stage64(Al, aL + k0, 512);
      stage64(Bh, bH + k0, 512);
      stage64(Bl, bL + k0, 512);
      __syncthreads();
      mfma64(Ah, Al, Bh, Bl, acc, lane, wid);
    }
  }
  #pragma unroll
  for(int r = 0; r < 4; r++){
    int x = wid*16 + (lane >> 4)*4 + r;
    if(x >= 60) continue;
    int i = y*60 + x;
    #pragma unroll
    for(int ct = 0; ct < 4; ct++){
      int c = n0 + ct*16 + (lane & 15);
      float v = acc[ct][r] + bcf[c];
      unsigned short h, l; split_bf(v, h, l);
      oH[(size_t)i*CC + c] = h; oL[(size_t)i*CC + c] = l;
    }
  }
}

// ---- GRU gates -------------------------------------------------------------
__global__ __launch_bounds__(256,4) void k_gates(char* ws, const float* __restrict__ bu, const float* __restrict__ br){
  __shared__ unsigned short Ah[64*72], Al[64*72], Bh[64*72], Bl[64*72];
  int z = blockIdx.z, m0 = blockIdx.x*64, n0 = blockIdx.y*64;
  const unsigned short* aH0 = WSPTR(const unsigned short, O_AH)  + (size_t)z*PP*CC;
  const unsigned short* aL0 = WSPTR(const unsigned short, O_AL)  + (size_t)z*PP*CC;
  const unsigned short* aH1 = WSPTR(const unsigned short, O_STH) + (size_t)z*PP*CC;
  const unsigned short* aL1 = WSPTR(const unsigned short, O_STL) + (size_t)z*PP*CC;
  const unsigned short* bH  = WSPTR(const unsigned short, O_WURH) + (size_t)n0*512;
  const unsigned short* bL  = WSPTR(const unsigned short, O_WURL) + (size_t)n0*512;
  const float* prevF = WSPTR(const float, O_SF) + (size_t)z*PP*CC;
  float* uOut = WSPTR(float, O_U) + (size_t)z*PP*CC;
  unsigned short* prH = WSPTR(unsigned short, O_PRH) + (size_t)z*PP*CC;
  unsigned short* prL = WSPTR(unsigned short, O_PRL) + (size_t)z*PP*CC;
  int lane = threadIdx.x & 63, wid = threadIdx.x >> 6;
  f32x4_t acc[4] = {};
  for(int ks = 0; ks < 8; ks++){
    const unsigned short* sah = (ks < 4) ? aH0 : aH1;
    const unsigned short* sal = (ks < 4) ? aL0 : aL1;
    int koff = (ks & 3) * 64;
    __syncthreads();
    stage64(Ah, sah + (size_t)m0*256 + koff, 256);
    stage64(Al, sal + (size_t)m0*256 + koff, 256);
    stage64(Bh, bH + ks*64, 512);
    stage64(Bl, bL + ks*64, 512);
    __syncthreads();
    mfma64(Ah, Al, Bh, Bl, acc, lane, wid);
  }
  #pragma unroll
  for(int r = 0; r < 4; r++){
    int i = m0 + wid*16 + (lane >> 4)*4 + r;
    if(i >= NP) continue;
    #pragma unroll
    for(int ct = 0; ct < 4; ct++){
      int c = n0 + ct*16 + (lane & 15);
      float pre = acc[ct][r] + (c < 256 ? bu[c] : br[c - 256]);
      float sg = 1.f / (1.f + __expf(-pre));
      if(c < 256){
        uOut[(size_t)i*CC + c] = sg;
      } else {
        int e = c - 256;
        float pv = prevF[(size_t)i*CC + e];
        unsigned short h, l; split_bf(sg * pv, h, l);
        prH[(size_t)i*CC + e] = h; prL[(size_t)i*CC + e] = l;
      }
    }
  }
}

// ---- GRU out ---------------------------------------------------------------
__global__ __launch_bounds__(256,4) void k_gruo(char* ws, const float* __restrict__ bo, float* __restrict__ dout, int fin){
  __shared__ unsigned short Ah[64*72], Al[64*72], Bh[64*72], Bl[64*72];
  int z = blockIdx.z, m0 = blockIdx.x*64, n0 = blockIdx.y*64;
  const unsigned short* aH0 = WSPTR(const unsigned short, O_AH)  + (size_t)z*PP*CC;
  const unsigned short* aL0 = WSPTR(const unsigned short, O_AL)  + (size_t)z*PP*CC;
  const unsigned short* aH1 = WSPTR(const unsigned short, O_PRH) + (size_t)z*PP*CC;
  const unsigned short* aL1 = WSPTR(const unsigned short, O_PRL) + (size_t)z*PP*CC;
  const unsigned short* bH  = WSPTR(const unsigned short, O_WOH) + (size_t)n0*512;
  const unsigned short* bL  = WSPTR(const unsigned short, O_WOL) + (size_t)n0*512;
  const float* uBuf = WSPTR(const float, O_U) + (size_t)z*PP*CC;
  float* sF = WSPTR(float, O_SF) + (size_t)z*PP*CC;
  unsigned short* sTh = WSPTR(unsigned short, O_STH) + (size_t)z*PP*CC;
  unsigned short* sTl = WSPTR(unsigned short, O_STL) + (size_t)z*PP*CC;
  unsigned short* sCh = WSPTR(unsigned short, O_SCH) + (size_t)z*PP*CC;
  unsigned short* sCl = WSPTR(unsigned short, O_SCL) + (size_t)z*PP*CC;
  int lane = threadIdx.x & 63, wid = threadIdx.x >> 6;
  f32x4_t acc[4] = {};
  for(int ks = 0; ks < 8; ks++){
    const unsigned short* sah = (ks < 4) ? aH0 : aH1;
    const unsigned short* sal = (ks < 4) ? aL0 : aL1;
    int koff = (ks & 3) * 64;
    __syncthreads();
    stage64(Ah, sah + (size_t)m0*256 + koff, 256);
    stage64(Al, sal + (size_t)m0*256 + koff, 256);
    stage64(Bh, bH + ks*64, 512);
    stage64(Bl, bL + ks*64, 512);
    __syncthreads();
    mfma64(Ah, Al, Bh, Bl, acc, lane, wid);
  }
  #pragma unroll
  for(int r = 0; r < 4; r++){
    int i = m0 + wid*16 + (lane >> 4)*4 + r;
    if(i >= NP) continue;
    #pragma unroll
    for(int ct = 0; ct < 4; ct++){
      int c = n0 + ct*16 + (lane & 15);
      float o = tanhf(acc[ct][r] + bo[c]);
      float uu = uBuf[(size_t)i*CC + c];
      float pv = sF[(size_t)i*CC + c];
      float h = pv*(1.f - uu) + o*uu;
      if(fin){
        dout[(size_t)z*921600 + (size_t)c*3600 + i] = h;
      } else {
        sF[(size_t)i*CC + c] = h;
        unsigned short hh, hl; split_bf(h, hh, hl);
        sTh[(size_t)i*CC + c] = hh; sTl[(size_t)i*CC + c] = hl;
        sCh[(size_t)c*PP + i] = hh; sCl[(size_t)c*PP + i] = hl;
      }
    }
  }
}

extern "C" void kernel_launch(void* const* d_in, const int* in_sizes, int n_in,
                              void* d_out, int out_size, void* d_ws, size_t ws_size,
                              hipStream_t stream){
  char* ws = (char*)d_ws;
  const float* in1   = (const float*)d_in[0];
  const float* in2   = (const float*)d_in[1];
  const float* in3   = (const float*)d_in[2];
  const float* Wlin  = (const float*)d_in[3];
  const float* Wgate = (const float*)d_in[4];
  const float* Wcf   = (const float*)d_in[5];
  const float* bcf   = (const float*)d_in[6];
  const float* Wr    = (const float*)d_in[7];
  const float* br_   = (const float*)d_in[8];
  const float* Wu    = (const float*)d_in[9];
  const float* bu_   = (const float*)d_in[10];
  const float* Wo    = (const float*)d_in[11];
  const float* bo_   = (const float*)d_in[12];

  // split-K factor limited by available workspace
  int nspl = 3;
  while(nspl > 1 && O_PO + (size_t)342*nspl*65536 > ws_size) nspl--;

  k_zero<<<dim3(2048), dim3(256), 0, stream>>>(ws);
  k_weights<<<dim3(1024), dim3(256), 0, stream>>>(ws, Wlin, Wu, Wr, Wo, Wcf);
  k_transpose<<<dim3(57, 4, 3), dim3(256), 0, stream>>>(ws, in1, in2, in3);

  for(int rd = 0; rd < 5; rd++){
    k_corr <<<dim3(57, 4, 3), dim3(256), 0, stream>>>(ws);
    k_flash<<<dim3(342*nspl), dim3(256), 0, stream>>>(ws, nspl);
    k_merge<<<dim3(57, 6), dim3(256), 0, stream>>>(ws, Wgate, nspl);
    k_conv <<<dim3(720), dim3(256), 0, stream>>>(ws, bcf);
    k_gates<<<dim3(57, 8, 3), dim3(256), 0, stream>>>(ws, bu_, br_);
    k_gruo <<<dim3(57, 4, 3), dim3(256), 0, stream>>>(ws, bo_, (float*)d_out, rd == 4 ? 1 : 0);
  }
}